// Round 11
// baseline (323.686 us; speedup 1.0000x reference)
//
#include <hip/hip_runtime.h>

#define HID 64
#define INDIM 128
#define NBUCK 256          // bucket = dst >> 9  (512 nodes/bucket)
#define EBUF_PER 10240     // fixed ebuf region per bucket (avg fill 8192)
#define CHUNK 4096         // edges per binA block

typedef unsigned short ushort_t;
typedef unsigned int uint_t;
typedef float floatx2 __attribute__((ext_vector_type(2)));

#if defined(__has_builtin)
#if __has_builtin(__builtin_amdgcn_cvt_pk_f32_fp8) && __has_builtin(__builtin_amdgcn_cvt_pk_fp8_f32)
#define USE_FP8 1
#endif
#endif
#ifndef USE_FP8
#define USE_FP8 0
#endif

__device__ __forceinline__ float softplusf(float x) {
    return fmaxf(x, 0.f) + log1pf(expf(-fabsf(x)));
}
__device__ __forceinline__ ushort_t f2bf(float f) {
    union { float f; uint_t i; } c; c.f = f;
    uint_t u = c.i;
    u += 0x7FFFu + ((u >> 16) & 1u);   // round to nearest even
    return (ushort_t)(u >> 16);
}
__device__ __forceinline__ float lo_bf(uint_t u) {
    union { uint_t i; float f; } c; c.i = u << 16; return c.f;
}
__device__ __forceinline__ float hi_bf(uint_t u) {
    union { uint_t i; float f; } c; c.i = u & 0xFFFF0000u; return c.f;
}

// ------ H = x @ W (quantized out) + zero cnt/smallb + init bcur ------------
// fp8: H row = 64 B (16 u32); bf16 fallback: row = 128 B (32 u32)
__global__ __launch_bounds__(256) void k_gemm(const float* __restrict__ x,
                                              const float* __restrict__ W,
                                              uint_t* __restrict__ Hq,
                                              int* __restrict__ cnt,
                                              float* __restrict__ smallb,
                                              int* __restrict__ bcur, int N) {
    __shared__ float Xs[64 * 132];
    __shared__ float Ws[128 * 64];
    int tid = threadIdx.x;
    int row0 = blockIdx.x * 64;

    if (tid < 64 && row0 + tid < N) cnt[row0 + tid] = 0;
    if (blockIdx.x == 0 && tid < 130) smallb[tid] = 0.f;
    if (blockIdx.x == 1 && tid < NBUCK) bcur[tid] = tid * EBUF_PER;

    const float4* W4 = (const float4*)W;
    float4* Ws4 = (float4*)Ws;
#pragma unroll
    for (int i = 0; i < 8; i++) Ws4[tid + 256 * i] = W4[tid + 256 * i];

#pragma unroll
    for (int i = 0; i < 8; i++) {
        int j = tid + 256 * i;
        int r = j >> 5, c4 = j & 31;
        int row = row0 + r;
        float4 v = make_float4(0.f, 0.f, 0.f, 0.f);
        if (row < N) v = *(const float4*)(x + row * INDIM + c4 * 4);
        *(float4*)(&Xs[r * 132 + c4 * 4]) = v;
    }
    __syncthreads();

    int tx = tid & 15;
    int ty = tid >> 4;
    float acc[4][4] = {};
    const float* xa = &Xs[(ty * 4) * 132];
#pragma unroll 4
    for (int k = 0; k < 128; k++) {
        float4 b = *(const float4*)(&Ws[k * 64 + tx * 4]);
#pragma unroll
        for (int i = 0; i < 4; i++) {
            float a = xa[i * 132 + k];
            acc[i][0] = fmaf(a, b.x, acc[i][0]);
            acc[i][1] = fmaf(a, b.y, acc[i][1]);
            acc[i][2] = fmaf(a, b.z, acc[i][2]);
            acc[i][3] = fmaf(a, b.w, acc[i][3]);
        }
    }
#pragma unroll
    for (int i = 0; i < 4; i++) {
        int row = row0 + ty * 4 + i;
        if (row < N) {
#if USE_FP8
            uint_t u = 0;
            u = __builtin_amdgcn_cvt_pk_fp8_f32(acc[i][0], acc[i][1], u, false);
            u = __builtin_amdgcn_cvt_pk_fp8_f32(acc[i][2], acc[i][3], u, true);
            Hq[(size_t)row * 16 + tx] = u;
#else
            uint_t u0 = ((uint_t)f2bf(acc[i][1]) << 16) | (uint_t)f2bf(acc[i][0]);
            uint_t u1 = ((uint_t)f2bf(acc[i][3]) << 16) | (uint_t)f2bf(acc[i][2]);
            Hq[(size_t)row * 32 + tx * 2] = u0;
            Hq[(size_t)row * 32 + tx * 2 + 1] = u1;
#endif
        }
    }
}

// ------ pass A: histogram + LDS-binned bucket scatter into ebuf ------------
__global__ __launch_bounds__(256) void k_binA(const int* __restrict__ src,
                                              const int* __restrict__ dst,
                                              int* __restrict__ cnt,
                                              int* __restrict__ bcur,
                                              int2* __restrict__ ebuf, int E) {
    __shared__ int lcnt[NBUCK];
    __shared__ int binStart[NBUCK];
    __shared__ int lofs[NBUCK];
    __shared__ int gofs[NBUCK];
    __shared__ int scan[NBUCK];
    __shared__ int2 stage[CHUNK];
    int tid = threadIdx.x;
    int base = blockIdx.x * CHUNK;

    lcnt[tid] = 0;
    __syncthreads();

    int sv[16], dv[16];
#pragma unroll
    for (int i = 0; i < 16; i++) {
        int e = base + i * 256 + tid;
        if (e < E) { sv[i] = src[e]; dv[i] = dst[e]; }
        else dv[i] = -1;
    }
#pragma unroll
    for (int i = 0; i < 16; i++) {
        if (dv[i] >= 0) {
            atomicAdd(&lcnt[dv[i] >> 9], 1);
            atomicAdd(&cnt[dv[i]], 1);          // fused global histogram
        }
    }
    __syncthreads();

    scan[tid] = lcnt[tid];
    __syncthreads();
    for (int off = 1; off < NBUCK; off <<= 1) {
        int v = (tid >= off) ? scan[tid - off] : 0;
        __syncthreads();
        scan[tid] += v;
        __syncthreads();
    }
    binStart[tid] = scan[tid] - lcnt[tid];
    lofs[tid] = binStart[tid];
    __syncthreads();

#pragma unroll
    for (int i = 0; i < 16; i++) {
        if (dv[i] >= 0) {
            int b = dv[i] >> 9;
            int p = atomicAdd(&lofs[b], 1);
            stage[p] = make_int2(sv[i], dv[i]);
        }
    }
    __syncthreads();

    if (lcnt[tid] > 0) gofs[tid] = atomicAdd(&bcur[tid], lcnt[tid]);
    __syncthreads();

    int total = (base + CHUNK <= E) ? CHUNK : (E > base ? E - base : 0);
    for (int idx = tid; idx < total; idx += 256) {
        int2 v = stage[idx];
        int b = v.y >> 9;
        ebuf[gofs[b] + (idx - binStart[b])] = v;
    }
}

// ---------------- scan stage 1: per-1024-chunk sums ------------------------
__global__ __launch_bounds__(256) void k_scan1(const int* __restrict__ cnt,
                                               int* __restrict__ partial, int N) {
    __shared__ int red[256];
    int base = blockIdx.x * 1024;
    int s = 0;
    for (int i = threadIdx.x; i < 1024; i += 256) {
        int idx = base + i;
        if (idx < N) s += cnt[idx];
    }
    red[threadIdx.x] = s;
    __syncthreads();
    for (int off = 128; off; off >>= 1) {
        if (threadIdx.x < off) red[threadIdx.x] += red[threadIdx.x + off];
        __syncthreads();
    }
    if (threadIdx.x == 0) partial[blockIdx.x] = red[0];
}

// ------ scan stage 2: redundant in-LDS scan of partials + per-chunk rowptr -
__global__ __launch_bounds__(256) void k_scan3(const int* __restrict__ cnt,
                                               const int* __restrict__ partial,
                                               int* __restrict__ rowptr,
                                               float* __restrict__ dinv,
                                               int N, int E) {
    __shared__ int sp[128];
    __shared__ int sc[256];
    int tid = threadIdx.x;
    int B98 = (N + 1023) >> 10;
    if (tid < 128) sp[tid] = (tid < B98) ? partial[tid] : 0;
    __syncthreads();
    for (int off = 1; off < 128; off <<= 1) {
        int v = (tid < 128 && tid >= off) ? sp[tid - off] : 0;
        __syncthreads();
        if (tid < 128) sp[tid] += v;
        __syncthreads();
    }
    int chunkEx = sp[blockIdx.x] - partial[blockIdx.x];
    __syncthreads();

    int base = blockIdx.x << 10;
    int i0 = base + tid * 4;
    int v0 = 0, v1 = 0, v2 = 0, v3 = 0;
    if (i0 + 3 < N) {
        int4 c = *(const int4*)(cnt + i0);
        v0 = c.x; v1 = c.y; v2 = c.z; v3 = c.w;
    } else {
        if (i0 < N)     v0 = cnt[i0];
        if (i0 + 1 < N) v1 = cnt[i0 + 1];
        if (i0 + 2 < N) v2 = cnt[i0 + 2];
        if (i0 + 3 < N) v3 = cnt[i0 + 3];
    }
    int s = v0 + v1 + v2 + v3;
    sc[tid] = s;
    __syncthreads();
    for (int off = 1; off < 256; off <<= 1) {
        int t = (tid >= off) ? sc[tid - off] : 0;
        __syncthreads();
        sc[tid] += t;
        __syncthreads();
    }
    int ex = sc[tid] - s + chunkEx;
    int r0 = ex, r1 = ex + v0, r2 = ex + v0 + v1, r3 = ex + v0 + v1 + v2;
    if (i0 < N)     { rowptr[i0]   = r0; dinv[i0]   = rsqrtf((float)(v0 + 1)); }
    if (i0 + 1 < N) { rowptr[i0+1] = r1; dinv[i0+1] = rsqrtf((float)(v1 + 1)); }
    if (i0 + 2 < N) { rowptr[i0+2] = r2; dinv[i0+2] = rsqrtf((float)(v2 + 1)); }
    if (i0 + 3 < N) { rowptr[i0+3] = r3; dinv[i0+3] = rsqrtf((float)(v3 + 1)); }
    if (blockIdx.x == 0 && tid == 0) rowptr[N] = E;
}

// ------ pass B: per-bucket exact placement with LDS cursor -----------------
__global__ __launch_bounds__(256) void k_binB(const int2* __restrict__ ebuf,
                                              const int* __restrict__ bcur,
                                              const int* __restrict__ rowptr,
                                              const int* __restrict__ perm,
                                              const float* __restrict__ dinv,
                                              int2* __restrict__ csrS,
                                              float* __restrict__ csrN, int N) {
    __shared__ int lcur[512];
    int tid = threadIdx.x;
    int b = blockIdx.x;
    int nodeBase = b << 9;
    for (int i = tid; i < 512; i += 256) {
        int n = nodeBase + i;
        lcur[i] = (n < N) ? rowptr[n] : 0;
    }
    __syncthreads();

    int start = b * EBUF_PER;
    int end = bcur[b];
    for (int idx = start + tid; idx < end; idx += 256) {
        int2 v = ebuf[idx];
        int s = v.x, d = v.y;
        int j = atomicAdd(&lcur[d & 511], 1);
        csrS[j] = make_int2(s, perm[s]);
        csrN[j] = dinv[s] * dinv[d];
    }
}

// ------ fused pull-gather ---------------------------------------------------
#if USE_FP8
// fp8 layout: H row = 16 u32 (64 B = ONE cache line).
// lane = (slot, sub): slot=lane>>4 in 0..3, sub=lane&15 covers dims 4*sub..4*sub+3
// slot0: edge j pos | slot1: edge j neg | slot2: edge j+1 pos | slot3: edge j+1 neg
__global__ __launch_bounds__(256) void k_gather(const uint_t* __restrict__ Hq,
                                                const int* __restrict__ rowptr,
                                                const int2* __restrict__ csrS,
                                                const float* __restrict__ csrN,
                                                const int* __restrict__ perm,
                                                const float* __restrict__ dinv,
                                                const float* __restrict__ b,
                                                const float* __restrict__ a,
                                                ushort_t* __restrict__ posb,
                                                ushort_t* __restrict__ negb,
                                                float* __restrict__ sumvec, int N) {
    int tid = threadIdx.x;
    int lane = tid & 63;
    int slot = lane >> 4;
    int sub = lane & 15;
    int isneg = slot & 1;
    int pair = slot >> 1;
    int wid = (blockIdx.x * 256 + tid) >> 6;
    int nw = gridDim.x * 4;
    float4 b4 = ((const float4*)b)[sub];
    float4 a4 = ((const float4*)a)[sub];
    float s0 = 0.f, s1 = 0.f, s2 = 0.f, s3 = 0.f;

    for (int n = wid; n < N; n += nw) {
        float dv = dinv[n];
        float w2 = dv * dv;
        int beg = rowptr[n], end = rowptr[n + 1];
        float a0 = 0.f, a1 = 0.f, a2 = 0.f, a3 = 0.f;
        int e0 = beg + pair;
        int2 ce = (e0 < end) ? csrS[e0] : make_int2(0, 0);
        float nm = (e0 < end) ? csrN[e0] : 0.f;
        for (int j = beg; j < end; j += 2) {
            int e1 = j + 2 + pair;
            int2 ceN = (e1 < end) ? csrS[e1] : make_int2(0, 0);
            float nmN = (e1 < end) ? csrN[e1] : 0.f;
            int row = isneg ? ce.y : ce.x;
            uint_t u = Hq[(size_t)row * 16 + sub];
            floatx2 lo = __builtin_amdgcn_cvt_pk_f32_fp8(u, false);
            floatx2 hi = __builtin_amdgcn_cvt_pk_f32_fp8(u, true);
            a0 = fmaf(lo.x, nm, a0);
            a1 = fmaf(lo.y, nm, a1);
            a2 = fmaf(hi.x, nm, a2);
            a3 = fmaf(hi.y, nm, a3);
            ce = ceN; nm = nmN;
        }
        // merge edge-pairs: lane^32 flips the pair bit (slot0<->2, slot1<->3)
        a0 += __shfl_xor(a0, 32);
        a1 += __shfl_xor(a1, 32);
        a2 += __shfl_xor(a2, 32);
        a3 += __shfl_xor(a3, 32);
        // self-loop + epilogue (lanes 0-31: slot0=pos, slot1=neg)
        int selfrow = isneg ? perm[n] : n;
        uint_t us = Hq[(size_t)selfrow * 16 + sub];
        floatx2 slo = __builtin_amdgcn_cvt_pk_f32_fp8(us, false);
        floatx2 shi = __builtin_amdgcn_cvt_pk_f32_fp8(us, true);
        float v0 = fmaf(slo.x, w2, a0) + b4.x;
        float v1 = fmaf(slo.y, w2, a1) + b4.y;
        float v2 = fmaf(shi.x, w2, a2) + b4.z;
        float v3 = fmaf(shi.y, w2, a3) + b4.w;
        v0 = v0 > 0.f ? v0 : v0 * a4.x;
        v1 = v1 > 0.f ? v1 : v1 * a4.y;
        v2 = v2 > 0.f ? v2 : v2 * a4.z;
        v3 = v3 > 0.f ? v3 : v3 * a4.w;
        if (lane < 32) {
            uint2 pk;
            pk.x = ((uint_t)f2bf(v1) << 16) | (uint_t)f2bf(v0);
            pk.y = ((uint_t)f2bf(v3) << 16) | (uint_t)f2bf(v2);
            uint2* outp = (uint2*)(isneg ? negb : posb);
            outp[(size_t)n * 16 + sub] = pk;
            if (!isneg) { s0 += v0; s1 += v1; s2 += v2; s3 += v3; }
        }
    }

    __shared__ float red[4][64];
    int w = tid >> 6;
    if (slot == 0) {
        red[w][sub * 4 + 0] = s0;
        red[w][sub * 4 + 1] = s1;
        red[w][sub * 4 + 2] = s2;
        red[w][sub * 4 + 3] = s3;
    }
    __syncthreads();
    if (tid < 64) {
        float s = red[0][tid] + red[1][tid] + red[2][tid] + red[3][tid];
        atomicAdd(&sumvec[tid], s);
    }
}
#else
// bf16 fallback (R10 gather): H row = 32 u32
__global__ __launch_bounds__(256) void k_gather(const uint_t* __restrict__ Hq,
                                                const int* __restrict__ rowptr,
                                                const int2* __restrict__ csrS,
                                                const float* __restrict__ csrN,
                                                const int* __restrict__ perm,
                                                const float* __restrict__ dinv,
                                                const float* __restrict__ b,
                                                const float* __restrict__ a,
                                                ushort_t* __restrict__ posb,
                                                ushort_t* __restrict__ negb,
                                                float* __restrict__ sumvec, int N) {
    int tid = threadIdx.x;
    int lane = tid & 63;
    int half = lane >> 5;
    int sub = lane & 31;
    int wid = (blockIdx.x * 256 + tid) >> 6;
    int nw = gridDim.x * 4;
    const uint_t* H32 = Hq;
    float2 b2 = ((const float2*)b)[sub];
    float2 a2 = ((const float2*)a)[sub];
    float sum0 = 0.f, sum1 = 0.f;

    for (int n = wid; n < N; n += nw) {
        float dv = dinv[n];
        float w2 = dv * dv;
        int beg = rowptr[n], end = rowptr[n + 1];
        float accP0 = 0.f, accP1 = 0.f, accN0 = 0.f, accN1 = 0.f;
        int eA = beg + half, eB = beg + 2 + half;
        bool vA = eA < end, vB = eB < end;
        int2 spA = vA ? csrS[eA] : make_int2(0, 0);
        int2 spB = vB ? csrS[eB] : make_int2(0, 0);
        float nmA = vA ? csrN[eA] : 0.f;
        float nmB = vB ? csrN[eB] : 0.f;
        for (int j = beg; j < end; j += 4) {
            int fA = j + 4 + half, fB = j + 6 + half;
            bool wA = fA < end, wB = fB < end;
            int2 npA = wA ? csrS[fA] : make_int2(0, 0);
            int2 npB = wB ? csrS[fB] : make_int2(0, 0);
            float nnA = wA ? csrN[fA] : 0.f;
            float nnB = wB ? csrN[fB] : 0.f;
            uint_t upA = H32[(size_t)spA.x * 32 + sub];
            uint_t unA = H32[(size_t)spA.y * 32 + sub];
            uint_t upB = H32[(size_t)spB.x * 32 + sub];
            uint_t unB = H32[(size_t)spB.y * 32 + sub];
            accP0 = fmaf(lo_bf(upA), nmA, accP0);
            accP1 = fmaf(hi_bf(upA), nmA, accP1);
            accN0 = fmaf(lo_bf(unA), nmA, accN0);
            accN1 = fmaf(hi_bf(unA), nmA, accN1);
            accP0 = fmaf(lo_bf(upB), nmB, accP0);
            accP1 = fmaf(hi_bf(upB), nmB, accP1);
            accN0 = fmaf(lo_bf(unB), nmB, accN0);
            accN1 = fmaf(hi_bf(unB), nmB, accN1);
            spA = npA; spB = npB; nmA = nnA; nmB = nnB;
        }
        accP0 += __shfl_xor(accP0, 32);
        accP1 += __shfl_xor(accP1, 32);
        accN0 += __shfl_xor(accN0, 32);
        accN1 += __shfl_xor(accN1, 32);
        int selfrow = half ? perm[n] : n;
        uint_t us = H32[(size_t)selfrow * 32 + sub];
        float e0 = half ? accN0 : accP0;
        float e1 = half ? accN1 : accP1;
        float v0 = fmaf(lo_bf(us), w2, e0) + b2.x;
        float v1 = fmaf(hi_bf(us), w2, e1) + b2.y;
        v0 = v0 > 0.f ? v0 : v0 * a2.x;
        v1 = v1 > 0.f ? v1 : v1 * a2.y;
        uint_t packed = ((uint_t)f2bf(v1) << 16) | (uint_t)f2bf(v0);
        uint_t* outp = (uint_t*)(half ? negb : posb);
        outp[(size_t)n * 32 + sub] = packed;
        if (!half) { sum0 += v0; sum1 += v1; }
    }

    __shared__ float red[4][64];
    int w = tid >> 6;
    if (!half) { red[w][2 * sub] = sum0; red[w][2 * sub + 1] = sum1; }
    __syncthreads();
    if (tid < 64) {
        float s = red[0][tid] + red[1][tid] + red[2][tid] + red[3][tid];
        atomicAdd(&sumvec[tid], s);
    }
}
#endif

// ------ loss with fused discriminator (svec computed per-block) ------------
__global__ __launch_bounds__(256) void k_loss(const ushort_t* __restrict__ posb,
                                              const ushort_t* __restrict__ negb,
                                              const float* __restrict__ sumvec,
                                              const float* __restrict__ Wd,
                                              float* __restrict__ lossAcc, int N) {
    __shared__ float summ[64];
    __shared__ float svecS[64];
    __shared__ float redL[8];
    int tid = threadIdx.x;
    if (tid < 64) summ[tid] = 1.f / (1.f + expf(-sumvec[tid] / (float)N));
    __syncthreads();
    if (tid < 64) {
        float s = 0.f;
#pragma unroll
        for (int j = 0; j < 64; j++) s += Wd[tid * 64 + j] * summ[j];
        svecS[tid] = s;
    }
    __syncthreads();

    int lane = tid & 63;
    int half = lane >> 5;
    int sub = lane & 31;
    int w = tid >> 6;
    float s0 = svecS[2 * sub], s1 = svecS[2 * sub + 1];
    const uint_t* P32 = (const uint_t*)(half ? negb : posb);
    float l = 0.f;
    int wid = (blockIdx.x * 256 + tid) >> 6;
    int nw = gridDim.x * 4;
    for (int n = wid; n < N; n += nw) {
        uint_t u = P32[(size_t)n * 32 + sub];
        float p = lo_bf(u) * s0 + hi_bf(u) * s1;
        p += __shfl_xor(p, 1);
        p += __shfl_xor(p, 2);
        p += __shfl_xor(p, 4);
        p += __shfl_xor(p, 8);
        p += __shfl_xor(p, 16);
        if (sub == 0) l += half ? softplusf(p) : softplusf(-p);
    }
    if (sub == 0) redL[w * 2 + half] = l;
    __syncthreads();
    if (tid == 0) {
        float t = 0.f;
#pragma unroll
        for (int i = 0; i < 8; i++) t += redL[i];
        atomicAdd(&lossAcc[0], t);
    }
}

// ---------------- final scalar ---------------------------------------------
__global__ void k_final(const float* __restrict__ lossAcc, float* __restrict__ out, int N) {
    out[0] = lossAcc[0] / (float)N;
}

extern "C" void kernel_launch(void* const* d_in, const int* in_sizes, int n_in,
                              void* d_out, int out_size, void* d_ws, size_t ws_size,
                              hipStream_t stream) {
    const float* x      = (const float*)d_in[0];
    const float* W_gcn  = (const float*)d_in[1];
    const float* b_gcn  = (const float*)d_in[2];
    const float* prelu_a= (const float*)d_in[3];
    const float* W_disc = (const float*)d_in[4];
    const int*   eidx   = (const int*)d_in[5];
    const int*   perm   = (const int*)d_in[6];

    int N = in_sizes[0] / INDIM;      // 100000
    int E = in_sizes[5] / 2;          // 1600000
    const int* src = eidx;
    const int* dst = eidx + E;

    char* base = (char*)d_ws;
    size_t off = 0;
    auto alloc = [&](size_t bytes) { size_t o = off; off = (off + bytes + 255) & ~(size_t)255; return o; };
    uint_t*   Hq    = (uint_t*)  (base + alloc((size_t)N * HID * 2));  // covers bf16 fallback too
    ushort_t* posb  = (ushort_t*)(base + alloc((size_t)N * HID * 2));
    ushort_t* negb  = (ushort_t*)(base + alloc((size_t)N * HID * 2));
    int2*     csrS  = (int2*)   (base + alloc((size_t)E * 8));
    float*    csrN  = (float*)  (base + alloc((size_t)E * 4));
    int2*     ebuf  = (int2*)   (base + alloc((size_t)NBUCK * EBUF_PER * 8));
    int*      cnt   = (int*)    (base + alloc((size_t)N * 4));
    float*    smallb= (float*)  (base + alloc(130 * 4));
    int*      rowptr= (int*)    (base + alloc(((size_t)N + 1) * 4));
    float*    dinv  = (float*)  (base + alloc((size_t)N * 4));
    int*      partial=(int*)    (base + alloc(128 * 4));
    int*      bcur  = (int*)    (base + alloc(NBUCK * 4));
    float* sumvec = smallb;
    float* lossAcc= smallb + 128;

    int B = (N + 1023) / 1024;            // 98
    int nbG = (N + 63) / 64;              // covers N for cnt zeroing
    int nbA = (E + CHUNK - 1) / CHUNK;    // 391
    int nbB = (N + 511) / 512;            // 196

    k_gemm<<<nbG, 256, 0, stream>>>(x, W_gcn, Hq, cnt, smallb, bcur, N);
    k_binA<<<nbA, 256, 0, stream>>>(src, dst, cnt, bcur, ebuf, E);
    k_scan1<<<B, 256, 0, stream>>>(cnt, partial, N);
    k_scan3<<<B, 256, 0, stream>>>(cnt, partial, rowptr, dinv, N, E);
    k_binB<<<nbB, 256, 0, stream>>>(ebuf, bcur, rowptr, perm, dinv, csrS, csrN, N);
    k_gather<<<2048, 256, 0, stream>>>(Hq, rowptr, csrS, csrN, perm, dinv,
                                       b_gcn, prelu_a, posb, negb, sumvec, N);
    k_loss<<<512, 256, 0, stream>>>(posb, negb, sumvec, W_disc, lossAcc, N);
    k_final<<<1, 1, 0, stream>>>(lossAcc, (float*)d_out, N);
}

// Round 12
// 306.360 us; speedup vs baseline: 1.0566x; 1.0566x over previous
//
#include <hip/hip_runtime.h>

#define HID 64
#define INDIM 128
#define NBUCK 256          // bucket = dst >> 9  (512 nodes/bucket)
#define EBUF_PER 10240     // fixed ebuf region per bucket (avg fill 8192)
#define CHUNK 4096         // edges per binA block

typedef unsigned short ushort_t;
typedef unsigned int uint_t;
typedef float floatx2 __attribute__((ext_vector_type(2)));

#if defined(__has_builtin)
#if __has_builtin(__builtin_amdgcn_cvt_pk_f32_fp8) && __has_builtin(__builtin_amdgcn_cvt_pk_fp8_f32)
#define USE_FP8 1
#endif
#endif
#ifndef USE_FP8
#define USE_FP8 0
#endif

__device__ __forceinline__ float softplusf(float x) {
    return fmaxf(x, 0.f) + log1pf(expf(-fabsf(x)));
}
__device__ __forceinline__ ushort_t f2bf(float f) {
    union { float f; uint_t i; } c; c.f = f;
    uint_t u = c.i;
    u += 0x7FFFu + ((u >> 16) & 1u);   // round to nearest even
    return (ushort_t)(u >> 16);
}
__device__ __forceinline__ float lo_bf(uint_t u) {
    union { uint_t i; float f; } c; c.i = u << 16; return c.f;
}
__device__ __forceinline__ float hi_bf(uint_t u) {
    union { uint_t i; float f; } c; c.i = u & 0xFFFF0000u; return c.f;
}

// ------ H = x @ W (quantized out) + zero cnt/smallb + init bcur ------------
__global__ __launch_bounds__(256) void k_gemm(const float* __restrict__ x,
                                              const float* __restrict__ W,
                                              uint_t* __restrict__ Hq,
                                              int* __restrict__ cnt,
                                              float* __restrict__ smallb,
                                              int* __restrict__ bcur, int N) {
    __shared__ float Xs[64 * 132];
    __shared__ float Ws[128 * 64];
    int tid = threadIdx.x;
    int row0 = blockIdx.x * 64;

    if (tid < 64 && row0 + tid < N) cnt[row0 + tid] = 0;
    if (blockIdx.x == 0 && tid < 130) smallb[tid] = 0.f;
    if (blockIdx.x == 1 && tid < NBUCK) bcur[tid] = tid * EBUF_PER;

    const float4* W4 = (const float4*)W;
    float4* Ws4 = (float4*)Ws;
#pragma unroll
    for (int i = 0; i < 8; i++) Ws4[tid + 256 * i] = W4[tid + 256 * i];

#pragma unroll
    for (int i = 0; i < 8; i++) {
        int j = tid + 256 * i;
        int r = j >> 5, c4 = j & 31;
        int row = row0 + r;
        float4 v = make_float4(0.f, 0.f, 0.f, 0.f);
        if (row < N) v = *(const float4*)(x + row * INDIM + c4 * 4);
        *(float4*)(&Xs[r * 132 + c4 * 4]) = v;
    }
    __syncthreads();

    int tx = tid & 15;
    int ty = tid >> 4;
    float acc[4][4] = {};
    const float* xa = &Xs[(ty * 4) * 132];
#pragma unroll 4
    for (int k = 0; k < 128; k++) {
        float4 b = *(const float4*)(&Ws[k * 64 + tx * 4]);
#pragma unroll
        for (int i = 0; i < 4; i++) {
            float a = xa[i * 132 + k];
            acc[i][0] = fmaf(a, b.x, acc[i][0]);
            acc[i][1] = fmaf(a, b.y, acc[i][1]);
            acc[i][2] = fmaf(a, b.z, acc[i][2]);
            acc[i][3] = fmaf(a, b.w, acc[i][3]);
        }
    }
#pragma unroll
    for (int i = 0; i < 4; i++) {
        int row = row0 + ty * 4 + i;
        if (row < N) {
#if USE_FP8
            uint_t u = 0;
            u = __builtin_amdgcn_cvt_pk_fp8_f32(acc[i][0], acc[i][1], u, false);
            u = __builtin_amdgcn_cvt_pk_fp8_f32(acc[i][2], acc[i][3], u, true);
            Hq[(size_t)row * 16 + tx] = u;
#else
            uint_t u0 = ((uint_t)f2bf(acc[i][1]) << 16) | (uint_t)f2bf(acc[i][0]);
            uint_t u1 = ((uint_t)f2bf(acc[i][3]) << 16) | (uint_t)f2bf(acc[i][2]);
            Hq[(size_t)row * 32 + tx * 2] = u0;
            Hq[(size_t)row * 32 + tx * 2 + 1] = u1;
#endif
        }
    }
}

// ------ pass A: histogram + LDS-binned bucket scatter into ebuf ------------
__global__ __launch_bounds__(256) void k_binA(const int* __restrict__ src,
                                              const int* __restrict__ dst,
                                              int* __restrict__ cnt,
                                              int* __restrict__ bcur,
                                              int2* __restrict__ ebuf, int E) {
    __shared__ int lcnt[NBUCK];
    __shared__ int binStart[NBUCK];
    __shared__ int lofs[NBUCK];
    __shared__ int gofs[NBUCK];
    __shared__ int scan[NBUCK];
    __shared__ int2 stage[CHUNK];
    int tid = threadIdx.x;
    int base = blockIdx.x * CHUNK;

    lcnt[tid] = 0;
    __syncthreads();

    int sv[16], dv[16];
#pragma unroll
    for (int i = 0; i < 16; i++) {
        int e = base + i * 256 + tid;
        if (e < E) { sv[i] = src[e]; dv[i] = dst[e]; }
        else dv[i] = -1;
    }
#pragma unroll
    for (int i = 0; i < 16; i++) {
        if (dv[i] >= 0) {
            atomicAdd(&lcnt[dv[i] >> 9], 1);
            atomicAdd(&cnt[dv[i]], 1);          // fused global histogram
        }
    }
    __syncthreads();

    scan[tid] = lcnt[tid];
    __syncthreads();
    for (int off = 1; off < NBUCK; off <<= 1) {
        int v = (tid >= off) ? scan[tid - off] : 0;
        __syncthreads();
        scan[tid] += v;
        __syncthreads();
    }
    binStart[tid] = scan[tid] - lcnt[tid];
    lofs[tid] = binStart[tid];
    __syncthreads();

#pragma unroll
    for (int i = 0; i < 16; i++) {
        if (dv[i] >= 0) {
            int b = dv[i] >> 9;
            int p = atomicAdd(&lofs[b], 1);
            stage[p] = make_int2(sv[i], dv[i]);
        }
    }
    __syncthreads();

    if (lcnt[tid] > 0) gofs[tid] = atomicAdd(&bcur[tid], lcnt[tid]);
    __syncthreads();

    int total = (base + CHUNK <= E) ? CHUNK : (E > base ? E - base : 0);
    for (int idx = tid; idx < total; idx += 256) {
        int2 v = stage[idx];
        int b = v.y >> 9;
        ebuf[gofs[b] + (idx - binStart[b])] = v;
    }
}

// ---------------- scan stage 1: per-1024-chunk sums ------------------------
__global__ __launch_bounds__(256) void k_scan1(const int* __restrict__ cnt,
                                               int* __restrict__ partial, int N) {
    __shared__ int red[256];
    int base = blockIdx.x * 1024;
    int s = 0;
    for (int i = threadIdx.x; i < 1024; i += 256) {
        int idx = base + i;
        if (idx < N) s += cnt[idx];
    }
    red[threadIdx.x] = s;
    __syncthreads();
    for (int off = 128; off; off >>= 1) {
        if (threadIdx.x < off) red[threadIdx.x] += red[threadIdx.x + off];
        __syncthreads();
    }
    if (threadIdx.x == 0) partial[blockIdx.x] = red[0];
}

// ------ scan stage 2: redundant in-LDS scan of partials + per-chunk rowptr -
__global__ __launch_bounds__(256) void k_scan3(const int* __restrict__ cnt,
                                               const int* __restrict__ partial,
                                               int* __restrict__ rowptr,
                                               float* __restrict__ dinv,
                                               int N, int E) {
    __shared__ int sp[128];
    __shared__ int sc[256];
    int tid = threadIdx.x;
    int B98 = (N + 1023) >> 10;
    if (tid < 128) sp[tid] = (tid < B98) ? partial[tid] : 0;
    __syncthreads();
    for (int off = 1; off < 128; off <<= 1) {
        int v = (tid < 128 && tid >= off) ? sp[tid - off] : 0;
        __syncthreads();
        if (tid < 128) sp[tid] += v;
        __syncthreads();
    }
    int chunkEx = sp[blockIdx.x] - partial[blockIdx.x];
    __syncthreads();

    int base = blockIdx.x << 10;
    int i0 = base + tid * 4;
    int v0 = 0, v1 = 0, v2 = 0, v3 = 0;
    if (i0 + 3 < N) {
        int4 c = *(const int4*)(cnt + i0);
        v0 = c.x; v1 = c.y; v2 = c.z; v3 = c.w;
    } else {
        if (i0 < N)     v0 = cnt[i0];
        if (i0 + 1 < N) v1 = cnt[i0 + 1];
        if (i0 + 2 < N) v2 = cnt[i0 + 2];
        if (i0 + 3 < N) v3 = cnt[i0 + 3];
    }
    int s = v0 + v1 + v2 + v3;
    sc[tid] = s;
    __syncthreads();
    for (int off = 1; off < 256; off <<= 1) {
        int t = (tid >= off) ? sc[tid - off] : 0;
        __syncthreads();
        sc[tid] += t;
        __syncthreads();
    }
    int ex = sc[tid] - s + chunkEx;
    int r0 = ex, r1 = ex + v0, r2 = ex + v0 + v1, r3 = ex + v0 + v1 + v2;
    if (i0 < N)     { rowptr[i0]   = r0; dinv[i0]   = rsqrtf((float)(v0 + 1)); }
    if (i0 + 1 < N) { rowptr[i0+1] = r1; dinv[i0+1] = rsqrtf((float)(v1 + 1)); }
    if (i0 + 2 < N) { rowptr[i0+2] = r2; dinv[i0+2] = rsqrtf((float)(v2 + 1)); }
    if (i0 + 3 < N) { rowptr[i0+3] = r3; dinv[i0+3] = rsqrtf((float)(v3 + 1)); }
    if (blockIdx.x == 0 && tid == 0) rowptr[N] = E;
}

// ------ pass B: per-bucket exact placement with LDS cursor -----------------
__global__ __launch_bounds__(256) void k_binB(const int2* __restrict__ ebuf,
                                              const int* __restrict__ bcur,
                                              const int* __restrict__ rowptr,
                                              const int* __restrict__ perm,
                                              const float* __restrict__ dinv,
                                              int2* __restrict__ csrS,
                                              float* __restrict__ csrN, int N) {
    __shared__ int lcur[512];
    int tid = threadIdx.x;
    int b = blockIdx.x;
    int nodeBase = b << 9;
    for (int i = tid; i < 512; i += 256) {
        int n = nodeBase + i;
        lcur[i] = (n < N) ? rowptr[n] : 0;
    }
    __syncthreads();

    int start = b * EBUF_PER;
    int end = bcur[b];
    for (int idx = start + tid; idx < end; idx += 256) {
        int2 v = ebuf[idx];
        int s = v.x, d = v.y;
        int j = atomicAdd(&lcur[d & 511], 1);
        csrS[j] = make_int2(s, perm[s]);
        csrN[j] = dinv[s] * dinv[d];
    }
}

// ------ fused pull-gather ---------------------------------------------------
#if USE_FP8
// fp8: H row = 16 u32 = 64 B = one line. lane = (slot, sub16):
// slot = (pair, isneg); load k covers edges j+2k+pair, view isneg
// -> each load instr = 4 rows x 64 B (perfect 256 B wave transaction).
// 8 edges per iteration, 4 independent H loads in flight.
__global__ __launch_bounds__(256) void k_gather(const uint_t* __restrict__ Hq,
                                                const int* __restrict__ rowptr,
                                                const int2* __restrict__ csrS,
                                                const float* __restrict__ csrN,
                                                const int* __restrict__ perm,
                                                const float* __restrict__ dinv,
                                                const float* __restrict__ b,
                                                const float* __restrict__ a,
                                                ushort_t* __restrict__ posb,
                                                ushort_t* __restrict__ negb,
                                                float* __restrict__ sumvec, int N) {
    int tid = threadIdx.x;
    int lane = tid & 63;
    int slot = lane >> 4;
    int sub = lane & 15;
    int isneg = slot & 1;
    int pair = slot >> 1;
    int wid = (blockIdx.x * 256 + tid) >> 6;
    int nw = gridDim.x * 4;
    float4 b4 = ((const float4*)b)[sub];
    float4 a4 = ((const float4*)a)[sub];
    float s0 = 0.f, s1 = 0.f, s2 = 0.f, s3 = 0.f;

    for (int n = wid; n < N; n += nw) {
        float dv = dinv[n];
        float w2 = dv * dv;
        int beg = rowptr[n], end = rowptr[n + 1];
        float a0 = 0.f, a1 = 0.f, a2 = 0.f, a3 = 0.f;
        // prologue: prefetch 4 entries (edges beg+2k+pair)
        int2 ce[4];
        float nm[4];
#pragma unroll
        for (int k = 0; k < 4; k++) {
            int e = beg + 2 * k + pair;
            bool v = e < end;
            ce[k] = v ? csrS[e] : make_int2(0, 0);
            nm[k] = v ? csrN[e] : 0.f;
        }
        for (int j = beg; j < end; j += 8) {
            int2 cn[4];
            float nn[4];
#pragma unroll
            for (int k = 0; k < 4; k++) {
                int e = j + 8 + 2 * k + pair;
                bool v = e < end;
                cn[k] = v ? csrS[e] : make_int2(0, 0);
                nn[k] = v ? csrN[e] : 0.f;
            }
            uint_t u[4];
#pragma unroll
            for (int k = 0; k < 4; k++) {
                int row = isneg ? ce[k].y : ce[k].x;
                u[k] = Hq[(size_t)row * 16 + sub];
            }
#pragma unroll
            for (int k = 0; k < 4; k++) {
                floatx2 lo = __builtin_amdgcn_cvt_pk_f32_fp8(u[k], false);
                floatx2 hi = __builtin_amdgcn_cvt_pk_f32_fp8(u[k], true);
                a0 = fmaf(lo.x, nm[k], a0);
                a1 = fmaf(lo.y, nm[k], a1);
                a2 = fmaf(hi.x, nm[k], a2);
                a3 = fmaf(hi.y, nm[k], a3);
            }
#pragma unroll
            for (int k = 0; k < 4; k++) { ce[k] = cn[k]; nm[k] = nn[k]; }
        }
        // merge pair bit (lane^32)
        a0 += __shfl_xor(a0, 32);
        a1 += __shfl_xor(a1, 32);
        a2 += __shfl_xor(a2, 32);
        a3 += __shfl_xor(a3, 32);
        // self-loop + epilogue (lanes 0-31: slot0=pos, slot1=neg)
        int selfrow = isneg ? perm[n] : n;
        uint_t us = Hq[(size_t)selfrow * 16 + sub];
        floatx2 slo = __builtin_amdgcn_cvt_pk_f32_fp8(us, false);
        floatx2 shi = __builtin_amdgcn_cvt_pk_f32_fp8(us, true);
        float v0 = fmaf(slo.x, w2, a0) + b4.x;
        float v1 = fmaf(slo.y, w2, a1) + b4.y;
        float v2 = fmaf(shi.x, w2, a2) + b4.z;
        float v3 = fmaf(shi.y, w2, a3) + b4.w;
        v0 = v0 > 0.f ? v0 : v0 * a4.x;
        v1 = v1 > 0.f ? v1 : v1 * a4.y;
        v2 = v2 > 0.f ? v2 : v2 * a4.z;
        v3 = v3 > 0.f ? v3 : v3 * a4.w;
        if (lane < 32) {
            uint2 pk;
            pk.x = ((uint_t)f2bf(v1) << 16) | (uint_t)f2bf(v0);
            pk.y = ((uint_t)f2bf(v3) << 16) | (uint_t)f2bf(v2);
            uint2* outp = (uint2*)(isneg ? negb : posb);
            outp[(size_t)n * 16 + sub] = pk;
            if (!isneg) { s0 += v0; s1 += v1; s2 += v2; s3 += v3; }
        }
    }

    __shared__ float red[4][64];
    int w = tid >> 6;
    if (slot == 0) {
        red[w][sub * 4 + 0] = s0;
        red[w][sub * 4 + 1] = s1;
        red[w][sub * 4 + 2] = s2;
        red[w][sub * 4 + 3] = s3;
    }
    __syncthreads();
    if (tid < 64) {
        float s = red[0][tid] + red[1][tid] + red[2][tid] + red[3][tid];
        atomicAdd(&sumvec[tid], s);
    }
}
#else
// bf16 fallback (R10 gather): H row = 32 u32
__global__ __launch_bounds__(256) void k_gather(const uint_t* __restrict__ Hq,
                                                const int* __restrict__ rowptr,
                                                const int2* __restrict__ csrS,
                                                const float* __restrict__ csrN,
                                                const int* __restrict__ perm,
                                                const float* __restrict__ dinv,
                                                const float* __restrict__ b,
                                                const float* __restrict__ a,
                                                ushort_t* __restrict__ posb,
                                                ushort_t* __restrict__ negb,
                                                float* __restrict__ sumvec, int N) {
    int tid = threadIdx.x;
    int lane = tid & 63;
    int half = lane >> 5;
    int sub = lane & 31;
    int wid = (blockIdx.x * 256 + tid) >> 6;
    int nw = gridDim.x * 4;
    const uint_t* H32 = Hq;
    float2 b2 = ((const float2*)b)[sub];
    float2 a2 = ((const float2*)a)[sub];
    float sum0 = 0.f, sum1 = 0.f;

    for (int n = wid; n < N; n += nw) {
        float dv = dinv[n];
        float w2 = dv * dv;
        int beg = rowptr[n], end = rowptr[n + 1];
        float accP0 = 0.f, accP1 = 0.f, accN0 = 0.f, accN1 = 0.f;
        int eA = beg + half, eB = beg + 2 + half;
        bool vA = eA < end, vB = eB < end;
        int2 spA = vA ? csrS[eA] : make_int2(0, 0);
        int2 spB = vB ? csrS[eB] : make_int2(0, 0);
        float nmA = vA ? csrN[eA] : 0.f;
        float nmB = vB ? csrN[eB] : 0.f;
        for (int j = beg; j < end; j += 4) {
            int fA = j + 4 + half, fB = j + 6 + half;
            bool wA = fA < end, wB = fB < end;
            int2 npA = wA ? csrS[fA] : make_int2(0, 0);
            int2 npB = wB ? csrS[fB] : make_int2(0, 0);
            float nnA = wA ? csrN[fA] : 0.f;
            float nnB = wB ? csrN[fB] : 0.f;
            uint_t upA = H32[(size_t)spA.x * 32 + sub];
            uint_t unA = H32[(size_t)spA.y * 32 + sub];
            uint_t upB = H32[(size_t)spB.x * 32 + sub];
            uint_t unB = H32[(size_t)spB.y * 32 + sub];
            accP0 = fmaf(lo_bf(upA), nmA, accP0);
            accP1 = fmaf(hi_bf(upA), nmA, accP1);
            accN0 = fmaf(lo_bf(unA), nmA, accN0);
            accN1 = fmaf(hi_bf(unA), nmA, accN1);
            accP0 = fmaf(lo_bf(upB), nmB, accP0);
            accP1 = fmaf(hi_bf(upB), nmB, accP1);
            accN0 = fmaf(lo_bf(unB), nmB, accN0);
            accN1 = fmaf(hi_bf(unB), nmB, accN1);
            spA = npA; spB = npB; nmA = nnA; nmB = nnB;
        }
        accP0 += __shfl_xor(accP0, 32);
        accP1 += __shfl_xor(accP1, 32);
        accN0 += __shfl_xor(accN0, 32);
        accN1 += __shfl_xor(accN1, 32);
        int selfrow = half ? perm[n] : n;
        uint_t us = H32[(size_t)selfrow * 32 + sub];
        float e0 = half ? accN0 : accP0;
        float e1 = half ? accN1 : accP1;
        float v0 = fmaf(lo_bf(us), w2, e0) + b2.x;
        float v1 = fmaf(hi_bf(us), w2, e1) + b2.y;
        v0 = v0 > 0.f ? v0 : v0 * a2.x;
        v1 = v1 > 0.f ? v1 : v1 * a2.y;
        uint_t packed = ((uint_t)f2bf(v1) << 16) | (uint_t)f2bf(v0);
        uint_t* outp = (uint_t*)(half ? negb : posb);
        outp[(size_t)n * 32 + sub] = packed;
        if (!half) { sum0 += v0; sum1 += v1; }
    }

    __shared__ float red[4][64];
    int w = tid >> 6;
    if (!half) { red[w][2 * sub] = sum0; red[w][2 * sub + 1] = sum1; }
    __syncthreads();
    if (tid < 64) {
        float s = red[0][tid] + red[1][tid] + red[2][tid] + red[3][tid];
        atomicAdd(&sumvec[tid], s);
    }
}
#endif

// ------ loss with fused discriminator (svec computed per-block) ------------
__global__ __launch_bounds__(256) void k_loss(const ushort_t* __restrict__ posb,
                                              const ushort_t* __restrict__ negb,
                                              const float* __restrict__ sumvec,
                                              const float* __restrict__ Wd,
                                              float* __restrict__ lossAcc, int N) {
    __shared__ float summ[64];
    __shared__ float svecS[64];
    __shared__ float redL[8];
    int tid = threadIdx.x;
    if (tid < 64) summ[tid] = 1.f / (1.f + expf(-sumvec[tid] / (float)N));
    __syncthreads();
    if (tid < 64) {
        float s = 0.f;
#pragma unroll
        for (int j = 0; j < 64; j++) s += Wd[tid * 64 + j] * summ[j];
        svecS[tid] = s;
    }
    __syncthreads();

    int lane = tid & 63;
    int half = lane >> 5;
    int sub = lane & 31;
    int w = tid >> 6;
    float s0 = svecS[2 * sub], s1 = svecS[2 * sub + 1];
    const uint_t* P32 = (const uint_t*)(half ? negb : posb);
    float l = 0.f;
    int wid = (blockIdx.x * 256 + tid) >> 6;
    int nw = gridDim.x * 4;
    for (int n = wid; n < N; n += nw) {
        uint_t u = P32[(size_t)n * 32 + sub];
        float p = lo_bf(u) * s0 + hi_bf(u) * s1;
        p += __shfl_xor(p, 1);
        p += __shfl_xor(p, 2);
        p += __shfl_xor(p, 4);
        p += __shfl_xor(p, 8);
        p += __shfl_xor(p, 16);
        if (sub == 0) l += half ? softplusf(p) : softplusf(-p);
    }
    if (sub == 0) redL[w * 2 + half] = l;
    __syncthreads();
    if (tid == 0) {
        float t = 0.f;
#pragma unroll
        for (int i = 0; i < 8; i++) t += redL[i];
        atomicAdd(&lossAcc[0], t);
    }
}

// ---------------- final scalar ---------------------------------------------
__global__ void k_final(const float* __restrict__ lossAcc, float* __restrict__ out, int N) {
    out[0] = lossAcc[0] / (float)N;
}

extern "C" void kernel_launch(void* const* d_in, const int* in_sizes, int n_in,
                              void* d_out, int out_size, void* d_ws, size_t ws_size,
                              hipStream_t stream) {
    const float* x      = (const float*)d_in[0];
    const float* W_gcn  = (const float*)d_in[1];
    const float* b_gcn  = (const float*)d_in[2];
    const float* prelu_a= (const float*)d_in[3];
    const float* W_disc = (const float*)d_in[4];
    const int*   eidx   = (const int*)d_in[5];
    const int*   perm   = (const int*)d_in[6];

    int N = in_sizes[0] / INDIM;      // 100000
    int E = in_sizes[5] / 2;          // 1600000
    const int* src = eidx;
    const int* dst = eidx + E;

    char* base = (char*)d_ws;
    size_t off = 0;
    auto alloc = [&](size_t bytes) { size_t o = off; off = (off + bytes + 255) & ~(size_t)255; return o; };
    uint_t*   Hq    = (uint_t*)  (base + alloc((size_t)N * HID * 2));  // covers bf16 fallback too
    ushort_t* posb  = (ushort_t*)(base + alloc((size_t)N * HID * 2));
    ushort_t* negb  = (ushort_t*)(base + alloc((size_t)N * HID * 2));
    int2*     csrS  = (int2*)   (base + alloc((size_t)E * 8));
    float*    csrN  = (float*)  (base + alloc((size_t)E * 4));
    int2*     ebuf  = (int2*)   (base + alloc((size_t)NBUCK * EBUF_PER * 8));
    int*      cnt   = (int*)    (base + alloc((size_t)N * 4));
    float*    smallb= (float*)  (base + alloc(130 * 4));
    int*      rowptr= (int*)    (base + alloc(((size_t)N + 1) * 4));
    float*    dinv  = (float*)  (base + alloc((size_t)N * 4));
    int*      partial=(int*)    (base + alloc(128 * 4));
    int*      bcur  = (int*)    (base + alloc(NBUCK * 4));
    float* sumvec = smallb;
    float* lossAcc= smallb + 128;

    int B = (N + 1023) / 1024;            // 98
    int nbG = (N + 63) / 64;              // covers N for cnt zeroing
    int nbA = (E + CHUNK - 1) / CHUNK;    // 391
    int nbB = (N + 511) / 512;            // 196

    k_gemm<<<nbG, 256, 0, stream>>>(x, W_gcn, Hq, cnt, smallb, bcur, N);
    k_binA<<<nbA, 256, 0, stream>>>(src, dst, cnt, bcur, ebuf, E);
    k_scan1<<<B, 256, 0, stream>>>(cnt, partial, N);
    k_scan3<<<B, 256, 0, stream>>>(cnt, partial, rowptr, dinv, N, E);
    k_binB<<<nbB, 256, 0, stream>>>(ebuf, bcur, rowptr, perm, dinv, csrS, csrN, N);
    k_gather<<<2048, 256, 0, stream>>>(Hq, rowptr, csrS, csrN, perm, dinv,
                                       b_gcn, prelu_a, posb, negb, sumvec, N);
    k_loss<<<512, 256, 0, stream>>>(posb, negb, sumvec, W_disc, lossAcc, N);
    k_final<<<1, 1, 0, stream>>>(lossAcc, (float*)d_out, N);
}

// Round 13
// 286.480 us; speedup vs baseline: 1.1299x; 1.0694x over previous
//
#include <hip/hip_runtime.h>

#define HID 64
#define INDIM 128
#define NBUCK 256          // bucket = dst >> 9  (512 nodes/bucket)
#define EBUF_PER 10240     // fixed ebuf region per bucket (avg fill 8192, 22 sigma)
#define CHUNK 4096         // edges per binA block

typedef unsigned short ushort_t;
typedef unsigned int uint_t;
typedef float floatx2 __attribute__((ext_vector_type(2)));

__device__ __forceinline__ float softplusf(float x) {
    return fmaxf(x, 0.f) + log1pf(expf(-fabsf(x)));
}
__device__ __forceinline__ ushort_t f2bf(float f) {
    union { float f; uint_t i; } c; c.f = f;
    uint_t u = c.i;
    u += 0x7FFFu + ((u >> 16) & 1u);
    return (ushort_t)(u >> 16);
}
__device__ __forceinline__ float lo_bf(uint_t u) {
    union { uint_t i; float f; } c; c.i = u << 16; return c.f;
}
__device__ __forceinline__ float hi_bf(uint_t u) {
    union { uint_t i; float f; } c; c.i = u & 0xFFFF0000u; return c.f;
}

// ===== K1: fused [binA (blocks 0..nbA) | gemm (rest)] ======================
// binA: LDS-binned bucket scatter of edges into ebuf (bcur = per-bucket count)
// gemm: H = x @ W -> fp8, row = 64 B
__global__ __launch_bounds__(256) void k_fused(const float* __restrict__ x,
                                               const float* __restrict__ W,
                                               const int* __restrict__ src,
                                               const int* __restrict__ dst,
                                               uint_t* __restrict__ Hq,
                                               int* __restrict__ bcur,
                                               int2* __restrict__ ebuf,
                                               int N, int E, int nbA) {
    __shared__ char lds[66560];
    int tid = threadIdx.x;

    if ((int)blockIdx.x < nbA) {
        // ---------------- binA ----------------
        int2* stage  = (int2*)lds;               // 32768
        int* lcnt    = (int*)(lds + 32768);      // 1024
        int* binSt   = (int*)(lds + 33792);      // 1024
        int* lofs    = (int*)(lds + 34816);      // 1024
        int* gofs    = (int*)(lds + 35840);      // 1024
        int* scn     = (int*)(lds + 36864);      // 1024
        int base = blockIdx.x * CHUNK;

        lcnt[tid] = 0;
        __syncthreads();

        int sv[16], dv[16];
#pragma unroll
        for (int i = 0; i < 16; i++) {
            int e = base + i * 256 + tid;
            if (e < E) { sv[i] = src[e]; dv[i] = dst[e]; }
            else dv[i] = -1;
        }
#pragma unroll
        for (int i = 0; i < 16; i++)
            if (dv[i] >= 0) atomicAdd(&lcnt[dv[i] >> 9], 1);
        __syncthreads();

        scn[tid] = lcnt[tid];
        __syncthreads();
        for (int off = 1; off < NBUCK; off <<= 1) {
            int v = (tid >= off) ? scn[tid - off] : 0;
            __syncthreads();
            scn[tid] += v;
            __syncthreads();
        }
        binSt[tid] = scn[tid] - lcnt[tid];
        lofs[tid] = binSt[tid];
        __syncthreads();

#pragma unroll
        for (int i = 0; i < 16; i++) {
            if (dv[i] >= 0) {
                int b = dv[i] >> 9;
                int p = atomicAdd(&lofs[b], 1);
                stage[p] = make_int2(sv[i], dv[i]);
            }
        }
        __syncthreads();

        if (lcnt[tid] > 0)
            gofs[tid] = tid * EBUF_PER + atomicAdd(&bcur[tid], lcnt[tid]);
        __syncthreads();

        int total = (base + CHUNK <= E) ? CHUNK : (E > base ? E - base : 0);
        for (int idx = tid; idx < total; idx += 256) {
            int2 v = stage[idx];
            int b = v.y >> 9;
            ebuf[gofs[b] + (idx - binSt[b])] = v;
        }
    } else {
        // ---------------- gemm ----------------
        float* Xs = (float*)lds;                 // 64*132*4 = 33792
        float* Ws = (float*)(lds + 33792);       // 128*64*4 = 32768
        int row0 = ((int)blockIdx.x - nbA) * 64;

        const float4* W4 = (const float4*)W;
        float4* Ws4 = (float4*)Ws;
#pragma unroll
        for (int i = 0; i < 8; i++) Ws4[tid + 256 * i] = W4[tid + 256 * i];

#pragma unroll
        for (int i = 0; i < 8; i++) {
            int j = tid + 256 * i;
            int r = j >> 5, c4 = j & 31;
            int row = row0 + r;
            float4 v = make_float4(0.f, 0.f, 0.f, 0.f);
            if (row < N) v = *(const float4*)(x + row * INDIM + c4 * 4);
            *(float4*)(&Xs[r * 132 + c4 * 4]) = v;
        }
        __syncthreads();

        int tx = tid & 15;
        int ty = tid >> 4;
        float acc[4][4] = {};
        const float* xa = &Xs[(ty * 4) * 132];
#pragma unroll 4
        for (int k = 0; k < 128; k++) {
            float4 b = *(const float4*)(&Ws[k * 64 + tx * 4]);
#pragma unroll
            for (int i = 0; i < 4; i++) {
                float a = xa[i * 132 + k];
                acc[i][0] = fmaf(a, b.x, acc[i][0]);
                acc[i][1] = fmaf(a, b.y, acc[i][1]);
                acc[i][2] = fmaf(a, b.z, acc[i][2]);
                acc[i][3] = fmaf(a, b.w, acc[i][3]);
            }
        }
#pragma unroll
        for (int i = 0; i < 4; i++) {
            int row = row0 + ty * 4 + i;
            if (row < N) {
                uint_t u = 0;
                u = __builtin_amdgcn_cvt_pk_fp8_f32(acc[i][0], acc[i][1], u, false);
                u = __builtin_amdgcn_cvt_pk_fp8_f32(acc[i][2], acc[i][3], u, true);
                Hq[(size_t)row * 16 + tx] = u;
            }
        }
    }
}

// ===== K2: binB — bucket-local rowptr/dinv + exact csr placement ===========
// block b owns nodes [b*512, b*512+512); no global cnt/scan needed.
__global__ __launch_bounds__(256) void k_binB(const int2* __restrict__ ebuf,
                                              const int* __restrict__ bcur,
                                              const int* __restrict__ perm,
                                              int2* __restrict__ csrS,
                                              int* __restrict__ rowptr,
                                              float* __restrict__ dinvg,
                                              int N, int E) {
    __shared__ int bb[NBUCK];
    __shared__ int sc[256];
    __shared__ int ldeg[512];
    __shared__ int lcur[512];
    int tid = threadIdx.x;
    int b = blockIdx.x;

    // bucket-base: inclusive scan of all bucket counts
    bb[tid] = bcur[tid];
    __syncthreads();
    for (int off = 1; off < NBUCK; off <<= 1) {
        int v = (tid >= off) ? bb[tid - off] : 0;
        __syncthreads();
        bb[tid] += v;
        __syncthreads();
    }
    int bucketBase = (b == 0) ? 0 : bb[b - 1];

    ldeg[tid] = 0;
    ldeg[tid + 256] = 0;
    __syncthreads();

    int start = b * EBUF_PER;
    int cb = bcur[b];
    for (int i = start + tid; i < start + cb; i += 256)
        atomicAdd(&ldeg[ebuf[i].y & 511], 1);
    __syncthreads();

    // scan 512 local degrees (2 per thread)
    int d0 = ldeg[2 * tid], d1 = ldeg[2 * tid + 1];
    int s2 = d0 + d1;
    sc[tid] = s2;
    __syncthreads();
    for (int off = 1; off < 256; off <<= 1) {
        int v = (tid >= off) ? sc[tid - off] : 0;
        __syncthreads();
        sc[tid] += v;
        __syncthreads();
    }
    int ex = sc[tid] - s2;
    int n0 = (b << 9) + 2 * tid, n1 = n0 + 1;
    int r0 = bucketBase + ex, r1 = r0 + d0;
    if (n0 < N) { rowptr[n0] = r0; dinvg[n0] = rsqrtf((float)(d0 + 1)); lcur[2 * tid] = r0; }
    if (n1 < N) { rowptr[n1] = r1; dinvg[n1] = rsqrtf((float)(d1 + 1)); lcur[2 * tid + 1] = r1; }
    if (b == 0 && tid == 0) rowptr[N] = E;
    __syncthreads();

    // place edges
    for (int i = start + tid; i < start + cb; i += 256) {
        int2 v = ebuf[i];
        int s = v.x;
        int j = atomicAdd(&lcur[v.y & 511], 1);
        csrS[j] = make_int2(s, perm[s]);
    }
}

// ===== K3: gather — fp8, slot layout, 8 edges/iter, scalar pipeline ========
// lane = (slot, sub16); slot = (pair, isneg). Each H load = 4 rows x 64 B.
__global__ __launch_bounds__(256) void k_gather(const uint_t* __restrict__ Hq,
                                                const int* __restrict__ rowptr,
                                                const int2* __restrict__ csrS,
                                                const int* __restrict__ perm,
                                                const float* __restrict__ dinv,
                                                const float* __restrict__ b,
                                                const float* __restrict__ a,
                                                ushort_t* __restrict__ posb,
                                                ushort_t* __restrict__ negb,
                                                float* __restrict__ sumvec, int N) {
    int tid = threadIdx.x;
    int lane = tid & 63;
    int slot = lane >> 4;
    int sub = lane & 15;
    int isneg = slot & 1;
    int pair = slot >> 1;
    int wid = (blockIdx.x * 256 + tid) >> 6;
    int nw = gridDim.x * 4;
    float4 b4 = ((const float4*)b)[sub];
    float4 a4 = ((const float4*)a)[sub];
    float s0 = 0.f, s1 = 0.f, s2 = 0.f, s3 = 0.f;

    for (int n = wid; n < N; n += nw) {
        float dv = dinv[n];
        float w2 = dv * dv;
        int beg = rowptr[n], end = rowptr[n + 1];
        float a0 = 0.f, a1 = 0.f, a2 = 0.f, a3 = 0.f;
        // prologue: 4 csr entries + their norms (named scalars, no arrays)
        int e0 = beg + pair, e1 = beg + 2 + pair, e2 = beg + 4 + pair, e3 = beg + 6 + pair;
        int2 c0 = (e0 < end) ? csrS[e0] : make_int2(0, 0);
        int2 c1 = (e1 < end) ? csrS[e1] : make_int2(0, 0);
        int2 c2 = (e2 < end) ? csrS[e2] : make_int2(0, 0);
        int2 c3 = (e3 < end) ? csrS[e3] : make_int2(0, 0);
        float m0 = (e0 < end) ? dinv[c0.x] * dv : 0.f;
        float m1 = (e1 < end) ? dinv[c1.x] * dv : 0.f;
        float m2 = (e2 < end) ? dinv[c2.x] * dv : 0.f;
        float m3 = (e3 < end) ? dinv[c3.x] * dv : 0.f;
        for (int j = beg; j < end; j += 8) {
            int f0 = j + 8 + pair, f1 = j + 10 + pair, f2 = j + 12 + pair, f3 = j + 14 + pair;
            int2 g0 = (f0 < end) ? csrS[f0] : make_int2(0, 0);
            int2 g1 = (f1 < end) ? csrS[f1] : make_int2(0, 0);
            int2 g2 = (f2 < end) ? csrS[f2] : make_int2(0, 0);
            int2 g3 = (f3 < end) ? csrS[f3] : make_int2(0, 0);
            uint_t u0 = Hq[(size_t)(isneg ? c0.y : c0.x) * 16 + sub];
            uint_t u1 = Hq[(size_t)(isneg ? c1.y : c1.x) * 16 + sub];
            uint_t u2 = Hq[(size_t)(isneg ? c2.y : c2.x) * 16 + sub];
            uint_t u3 = Hq[(size_t)(isneg ? c3.y : c3.x) * 16 + sub];
            float q0 = (f0 < end) ? dinv[g0.x] * dv : 0.f;
            float q1 = (f1 < end) ? dinv[g1.x] * dv : 0.f;
            float q2 = (f2 < end) ? dinv[g2.x] * dv : 0.f;
            float q3 = (f3 < end) ? dinv[g3.x] * dv : 0.f;
            floatx2 lo, hi;
            lo = __builtin_amdgcn_cvt_pk_f32_fp8(u0, false);
            hi = __builtin_amdgcn_cvt_pk_f32_fp8(u0, true);
            a0 = fmaf(lo.x, m0, a0); a1 = fmaf(lo.y, m0, a1);
            a2 = fmaf(hi.x, m0, a2); a3 = fmaf(hi.y, m0, a3);
            lo = __builtin_amdgcn_cvt_pk_f32_fp8(u1, false);
            hi = __builtin_amdgcn_cvt_pk_f32_fp8(u1, true);
            a0 = fmaf(lo.x, m1, a0); a1 = fmaf(lo.y, m1, a1);
            a2 = fmaf(hi.x, m1, a2); a3 = fmaf(hi.y, m1, a3);
            lo = __builtin_amdgcn_cvt_pk_f32_fp8(u2, false);
            hi = __builtin_amdgcn_cvt_pk_f32_fp8(u2, true);
            a0 = fmaf(lo.x, m2, a0); a1 = fmaf(lo.y, m2, a1);
            a2 = fmaf(hi.x, m2, a2); a3 = fmaf(hi.y, m2, a3);
            lo = __builtin_amdgcn_cvt_pk_f32_fp8(u3, false);
            hi = __builtin_amdgcn_cvt_pk_f32_fp8(u3, true);
            a0 = fmaf(lo.x, m3, a0); a1 = fmaf(lo.y, m3, a1);
            a2 = fmaf(hi.x, m3, a2); a3 = fmaf(hi.y, m3, a3);
            c0 = g0; c1 = g1; c2 = g2; c3 = g3;
            m0 = q0; m1 = q1; m2 = q2; m3 = q3;
        }
        // merge pair halves (lane^32)
        a0 += __shfl_xor(a0, 32);
        a1 += __shfl_xor(a1, 32);
        a2 += __shfl_xor(a2, 32);
        a3 += __shfl_xor(a3, 32);
        // self-loop + epilogue (lanes 0-31: slot0=pos, slot1=neg)
        int selfrow = isneg ? perm[n] : n;
        uint_t us = Hq[(size_t)selfrow * 16 + sub];
        floatx2 slo = __builtin_amdgcn_cvt_pk_f32_fp8(us, false);
        floatx2 shi = __builtin_amdgcn_cvt_pk_f32_fp8(us, true);
        float v0 = fmaf(slo.x, w2, a0) + b4.x;
        float v1 = fmaf(slo.y, w2, a1) + b4.y;
        float v2 = fmaf(shi.x, w2, a2) + b4.z;
        float v3 = fmaf(shi.y, w2, a3) + b4.w;
        v0 = v0 > 0.f ? v0 : v0 * a4.x;
        v1 = v1 > 0.f ? v1 : v1 * a4.y;
        v2 = v2 > 0.f ? v2 : v2 * a4.z;
        v3 = v3 > 0.f ? v3 : v3 * a4.w;
        if (lane < 32) {
            uint2 pk;
            pk.x = ((uint_t)f2bf(v1) << 16) | (uint_t)f2bf(v0);
            pk.y = ((uint_t)f2bf(v3) << 16) | (uint_t)f2bf(v2);
            uint2* outp = (uint2*)(isneg ? negb : posb);
            outp[(size_t)n * 16 + sub] = pk;
            if (!isneg) { s0 += v0; s1 += v1; s2 += v2; s3 += v3; }
        }
    }

    __shared__ float red[4][64];
    int w = tid >> 6;
    if (slot == 0) {
        red[w][sub * 4 + 0] = s0;
        red[w][sub * 4 + 1] = s1;
        red[w][sub * 4 + 2] = s2;
        red[w][sub * 4 + 3] = s3;
    }
    __syncthreads();
    if (tid < 64) {
        float s = red[0][tid] + red[1][tid] + red[2][tid] + red[3][tid];
        atomicAdd(&sumvec[tid], s);
    }
}

// ===== K4: loss (disc fused) + last-block final ============================
__global__ __launch_bounds__(256) void k_loss(const ushort_t* __restrict__ posb,
                                              const ushort_t* __restrict__ negb,
                                              float* __restrict__ smallb,
                                              const float* __restrict__ Wd,
                                              float* __restrict__ out, int N) {
    __shared__ float summ[64];
    __shared__ float svecS[64];
    __shared__ float redL[8];
    int tid = threadIdx.x;
    float* sumvec = smallb;
    float* lossAcc = smallb + 128;
    int* done = (int*)(smallb + 129);

    if (tid < 64) summ[tid] = 1.f / (1.f + expf(-sumvec[tid] / (float)N));
    __syncthreads();
    if (tid < 64) {
        float s = 0.f;
#pragma unroll
        for (int j = 0; j < 64; j++) s += Wd[tid * 64 + j] * summ[j];
        svecS[tid] = s;
    }
    __syncthreads();

    int lane = tid & 63;
    int half = lane >> 5;
    int sub = lane & 31;
    int w = tid >> 6;
    float s0 = svecS[2 * sub], s1 = svecS[2 * sub + 1];
    const uint_t* P32 = (const uint_t*)(half ? negb : posb);
    float l = 0.f;
    int wid = (blockIdx.x * 256 + tid) >> 6;
    int nw = gridDim.x * 4;
    for (int n = wid; n < N; n += nw) {
        uint_t u = P32[(size_t)n * 32 + sub];
        float p = lo_bf(u) * s0 + hi_bf(u) * s1;
        p += __shfl_xor(p, 1);
        p += __shfl_xor(p, 2);
        p += __shfl_xor(p, 4);
        p += __shfl_xor(p, 8);
        p += __shfl_xor(p, 16);
        if (sub == 0) l += half ? softplusf(p) : softplusf(-p);
    }
    if (sub == 0) redL[w * 2 + half] = l;
    __syncthreads();
    if (tid == 0) {
        float t = 0.f;
#pragma unroll
        for (int i = 0; i < 8; i++) t += redL[i];
        atomicAdd(&lossAcc[0], t);
        __threadfence();
        int old = atomicAdd(done, 1);
        if (old == (int)gridDim.x - 1) {
            float tot = atomicAdd(&lossAcc[0], 0.f);   // coherent read of final sum
            out[0] = tot / (float)N;
        }
    }
}

extern "C" void kernel_launch(void* const* d_in, const int* in_sizes, int n_in,
                              void* d_out, int out_size, void* d_ws, size_t ws_size,
                              hipStream_t stream) {
    const float* x      = (const float*)d_in[0];
    const float* W_gcn  = (const float*)d_in[1];
    const float* b_gcn  = (const float*)d_in[2];
    const float* prelu_a= (const float*)d_in[3];
    const float* W_disc = (const float*)d_in[4];
    const int*   eidx   = (const int*)d_in[5];
    const int*   perm   = (const int*)d_in[6];

    int N = in_sizes[0] / INDIM;      // 100000
    int E = in_sizes[5] / 2;          // 1600000
    const int* src = eidx;
    const int* dst = eidx + E;

    char* base = (char*)d_ws;
    size_t off = 0;
    auto alloc = [&](size_t bytes) { size_t o = off; off = (off + bytes + 255) & ~(size_t)255; return o; };
    uint_t*   Hq    = (uint_t*)  (base + alloc((size_t)N * HID));        // fp8: 6.4 MB
    ushort_t* posb  = (ushort_t*)(base + alloc((size_t)N * HID * 2));
    ushort_t* negb  = (ushort_t*)(base + alloc((size_t)N * HID * 2));
    int2*     csrS  = (int2*)   (base + alloc((size_t)E * 8));
    int2*     ebuf  = (int2*)   (base + alloc((size_t)NBUCK * EBUF_PER * 8));
    int*      rowptr= (int*)    (base + alloc(((size_t)N + 1) * 4));
    float*    dinv  = (float*)  (base + alloc((size_t)N * 4));
    // zero region: bcur[NBUCK] + smallb[132] contiguous
    size_t zOff = alloc(NBUCK * 4 + 132 * 4);
    int*      bcur  = (int*)(base + zOff);
    float*    smallb= (float*)(base + zOff + NBUCK * 4);
    float* sumvec = smallb;

    int nbA = (E + CHUNK - 1) / CHUNK;    // 391
    int nbG = (N + 63) / 64;              // 1563
    int nbB = (N + 511) / 512;            // 196

    hipMemsetAsync(bcur, 0, NBUCK * 4 + 132 * 4, stream);
    k_fused<<<nbA + nbG, 256, 0, stream>>>(x, W_gcn, src, dst, Hq, bcur, ebuf, N, E, nbA);
    k_binB<<<nbB, 256, 0, stream>>>(ebuf, bcur, perm, csrS, rowptr, dinv, N, E);
    k_gather<<<2048, 256, 0, stream>>>(Hq, rowptr, csrS, perm, dinv,
                                       b_gcn, prelu_a, posb, negb, sumvec, N);
    k_loss<<<512, 256, 0, stream>>>(posb, negb, smallb, W_disc, (float*)d_out, N);
}

// Round 14
// 262.059 us; speedup vs baseline: 1.2352x; 1.0932x over previous
//
#include <hip/hip_runtime.h>

#define HID 64
#define INDIM 128
#define NBUCK 256          // bucket = dst >> 9  (512 nodes/bucket)
#define EBUF_PER 10240     // fixed ebuf region per bucket (avg fill 8192, 22 sigma)
#define CHUNK 4096         // edges per binA block

typedef unsigned short ushort_t;
typedef unsigned int uint_t;
typedef float floatx2 __attribute__((ext_vector_type(2)));

__device__ __forceinline__ float softplusf(float x) {
    return fmaxf(x, 0.f) + log1pf(expf(-fabsf(x)));
}
__device__ __forceinline__ ushort_t f2bf(float f) {
    union { float f; uint_t i; } c; c.f = f;
    uint_t u = c.i;
    u += 0x7FFFu + ((u >> 16) & 1u);
    return (ushort_t)(u >> 16);
}
__device__ __forceinline__ float lo_bf(uint_t u) {
    union { uint_t i; float f; } c; c.i = u << 16; return c.f;
}
__device__ __forceinline__ float hi_bf(uint_t u) {
    union { uint_t i; float f; } c; c.i = u & 0xFFFF0000u; return c.f;
}

// ===== K1: fused [binA (blocks 0..nbA) | gemm (rest)] ======================
__global__ __launch_bounds__(256) void k_fused(const float* __restrict__ x,
                                               const float* __restrict__ W,
                                               const int* __restrict__ src,
                                               const int* __restrict__ dst,
                                               uint_t* __restrict__ Hq,
                                               int* __restrict__ bcur,
                                               int2* __restrict__ ebuf,
                                               int N, int E, int nbA) {
    __shared__ char lds[66560];
    int tid = threadIdx.x;

    if ((int)blockIdx.x < nbA) {
        // ---------------- binA ----------------
        int2* stage  = (int2*)lds;               // 32768
        int* lcnt    = (int*)(lds + 32768);
        int* binSt   = (int*)(lds + 33792);
        int* lofs    = (int*)(lds + 34816);
        int* gofs    = (int*)(lds + 35840);
        int* scn     = (int*)(lds + 36864);
        int base = blockIdx.x * CHUNK;

        lcnt[tid] = 0;
        __syncthreads();

        int sv[16], dv[16];
#pragma unroll
        for (int i = 0; i < 16; i++) {
            int e = base + i * 256 + tid;
            if (e < E) { sv[i] = src[e]; dv[i] = dst[e]; }
            else dv[i] = -1;
        }
#pragma unroll
        for (int i = 0; i < 16; i++)
            if (dv[i] >= 0) atomicAdd(&lcnt[dv[i] >> 9], 1);
        __syncthreads();

        scn[tid] = lcnt[tid];
        __syncthreads();
        for (int off = 1; off < NBUCK; off <<= 1) {
            int v = (tid >= off) ? scn[tid - off] : 0;
            __syncthreads();
            scn[tid] += v;
            __syncthreads();
        }
        binSt[tid] = scn[tid] - lcnt[tid];
        lofs[tid] = binSt[tid];
        __syncthreads();

#pragma unroll
        for (int i = 0; i < 16; i++) {
            if (dv[i] >= 0) {
                int b = dv[i] >> 9;
                int p = atomicAdd(&lofs[b], 1);
                stage[p] = make_int2(sv[i], dv[i]);
            }
        }
        __syncthreads();

        if (lcnt[tid] > 0)
            gofs[tid] = tid * EBUF_PER + atomicAdd(&bcur[tid], lcnt[tid]);
        __syncthreads();

        int total = (base + CHUNK <= E) ? CHUNK : (E > base ? E - base : 0);
        for (int idx = tid; idx < total; idx += 256) {
            int2 v = stage[idx];
            int b = v.y >> 9;
            ebuf[gofs[b] + (idx - binSt[b])] = v;
        }
    } else {
        // ---------------- gemm ----------------
        float* Xs = (float*)lds;                 // 33792
        float* Ws = (float*)(lds + 33792);       // 32768
        int row0 = ((int)blockIdx.x - nbA) * 64;

        const float4* W4 = (const float4*)W;
        float4* Ws4 = (float4*)Ws;
#pragma unroll
        for (int i = 0; i < 8; i++) Ws4[tid + 256 * i] = W4[tid + 256 * i];

#pragma unroll
        for (int i = 0; i < 8; i++) {
            int j = tid + 256 * i;
            int r = j >> 5, c4 = j & 31;
            int row = row0 + r;
            float4 v = make_float4(0.f, 0.f, 0.f, 0.f);
            if (row < N) v = *(const float4*)(x + row * INDIM + c4 * 4);
            *(float4*)(&Xs[r * 132 + c4 * 4]) = v;
        }
        __syncthreads();

        int tx = tid & 15;
        int ty = tid >> 4;
        float acc[4][4] = {};
        const float* xa = &Xs[(ty * 4) * 132];
#pragma unroll 4
        for (int k = 0; k < 128; k++) {
            float4 b = *(const float4*)(&Ws[k * 64 + tx * 4]);
#pragma unroll
            for (int i = 0; i < 4; i++) {
                float a = xa[i * 132 + k];
                acc[i][0] = fmaf(a, b.x, acc[i][0]);
                acc[i][1] = fmaf(a, b.y, acc[i][1]);
                acc[i][2] = fmaf(a, b.z, acc[i][2]);
                acc[i][3] = fmaf(a, b.w, acc[i][3]);
            }
        }
#pragma unroll
        for (int i = 0; i < 4; i++) {
            int row = row0 + ty * 4 + i;
            if (row < N) {
                uint_t u = 0;
                u = __builtin_amdgcn_cvt_pk_fp8_f32(acc[i][0], acc[i][1], u, false);
                u = __builtin_amdgcn_cvt_pk_fp8_f32(acc[i][2], acc[i][3], u, true);
                Hq[(size_t)row * 16 + tx] = u;
            }
        }
    }
}

// ===== K2: binB1 — per-bucket degrees -> rowptr, dinv ======================
__global__ __launch_bounds__(256) void k_binB1(const int2* __restrict__ ebuf,
                                               const int* __restrict__ bcur,
                                               int* __restrict__ rowptr,
                                               float* __restrict__ dinvg,
                                               int N, int E) {
    __shared__ int bb[NBUCK];
    __shared__ int sc[256];
    __shared__ int ldeg[512];
    int tid = threadIdx.x;
    int b = blockIdx.x;

    bb[tid] = bcur[tid];
    __syncthreads();
    for (int off = 1; off < NBUCK; off <<= 1) {
        int v = (tid >= off) ? bb[tid - off] : 0;
        __syncthreads();
        bb[tid] += v;
        __syncthreads();
    }
    int bucketBase = (b == 0) ? 0 : bb[b - 1];

    ldeg[tid] = 0;
    ldeg[tid + 256] = 0;
    __syncthreads();

    int start = b * EBUF_PER;
    int cb = bcur[b];
    for (int i = start + tid; i < start + cb; i += 256)
        atomicAdd(&ldeg[ebuf[i].y & 511], 1);
    __syncthreads();

    int d0 = ldeg[2 * tid], d1 = ldeg[2 * tid + 1];
    int s2 = d0 + d1;
    sc[tid] = s2;
    __syncthreads();
    for (int off = 1; off < 256; off <<= 1) {
        int v = (tid >= off) ? sc[tid - off] : 0;
        __syncthreads();
        sc[tid] += v;
        __syncthreads();
    }
    int ex = sc[tid] - s2;
    int n0 = (b << 9) + 2 * tid, n1 = n0 + 1;
    int r0 = bucketBase + ex, r1 = r0 + d0;
    if (n0 < N) { rowptr[n0] = r0; dinvg[n0] = rsqrtf((float)(d0 + 1)); }
    if (n1 < N) { rowptr[n1] = r1; dinvg[n1] = rsqrtf((float)(d1 + 1)); }
    if (b == 0 && tid == 0) rowptr[N] = E;
}

// ===== K3: binB2 — exact csr placement + precomputed norms =================
__global__ __launch_bounds__(256) void k_binB2(const int2* __restrict__ ebuf,
                                               const int* __restrict__ bcur,
                                               const int* __restrict__ rowptr,
                                               const int* __restrict__ perm,
                                               const float* __restrict__ dinvg,
                                               int2* __restrict__ csrS,
                                               float* __restrict__ csrN, int N) {
    __shared__ int lcur[512];
    __shared__ float ldinv[512];
    int tid = threadIdx.x;
    int b = blockIdx.x;
    int nodeBase = b << 9;
    for (int i = tid; i < 512; i += 256) {
        int n = nodeBase + i;
        lcur[i] = (n < N) ? rowptr[n] : 0;
        ldinv[i] = (n < N) ? dinvg[n] : 0.f;
    }
    __syncthreads();

    int start = b * EBUF_PER;
    int cb = bcur[b];
    for (int i = start + tid; i < start + cb; i += 256) {
        int2 v = ebuf[i];
        int s = v.x, dl = v.y & 511;
        int j = atomicAdd(&lcur[dl], 1);
        csrS[j] = make_int2(s, perm[s]);
        csrN[j] = dinvg[s] * ldinv[dl];
    }
}

// ===== K4: gather — fp8, slot layout, 8 edges/iter, csrN, scalar regs ======
// lane = (slot, sub16); slot = (pair, isneg). Each H load = 4 rows x 64 B.
__global__ __launch_bounds__(256) void k_gather(const uint_t* __restrict__ Hq,
                                                const int* __restrict__ rowptr,
                                                const int2* __restrict__ csrS,
                                                const float* __restrict__ csrN,
                                                const int* __restrict__ perm,
                                                const float* __restrict__ dinv,
                                                const float* __restrict__ b,
                                                const float* __restrict__ a,
                                                ushort_t* __restrict__ posb,
                                                ushort_t* __restrict__ negb,
                                                float* __restrict__ sumvec, int N) {
    int tid = threadIdx.x;
    int lane = tid & 63;
    int slot = lane >> 4;
    int sub = lane & 15;
    int isneg = slot & 1;
    int pair = slot >> 1;
    int wid = (blockIdx.x * 256 + tid) >> 6;
    int nw = gridDim.x * 4;
    float4 b4 = ((const float4*)b)[sub];
    float4 a4 = ((const float4*)a)[sub];
    float s0 = 0.f, s1 = 0.f, s2 = 0.f, s3 = 0.f;

    for (int n = wid; n < N; n += nw) {
        float dv = dinv[n];
        float w2 = dv * dv;
        int beg = rowptr[n], end = rowptr[n + 1];
        float a0 = 0.f, a1 = 0.f, a2 = 0.f, a3 = 0.f;
        int e0 = beg + pair, e1 = beg + 2 + pair, e2 = beg + 4 + pair, e3 = beg + 6 + pair;
        int2 c0 = (e0 < end) ? csrS[e0] : make_int2(0, 0);
        int2 c1 = (e1 < end) ? csrS[e1] : make_int2(0, 0);
        int2 c2 = (e2 < end) ? csrS[e2] : make_int2(0, 0);
        int2 c3 = (e3 < end) ? csrS[e3] : make_int2(0, 0);
        float m0 = (e0 < end) ? csrN[e0] : 0.f;
        float m1 = (e1 < end) ? csrN[e1] : 0.f;
        float m2 = (e2 < end) ? csrN[e2] : 0.f;
        float m3 = (e3 < end) ? csrN[e3] : 0.f;
        for (int j = beg; j < end; j += 8) {
            int f0 = j + 8 + pair, f1 = j + 10 + pair, f2 = j + 12 + pair, f3 = j + 14 + pair;
            int2 g0 = (f0 < end) ? csrS[f0] : make_int2(0, 0);
            int2 g1 = (f1 < end) ? csrS[f1] : make_int2(0, 0);
            int2 g2 = (f2 < end) ? csrS[f2] : make_int2(0, 0);
            int2 g3 = (f3 < end) ? csrS[f3] : make_int2(0, 0);
            float q0 = (f0 < end) ? csrN[f0] : 0.f;
            float q1 = (f1 < end) ? csrN[f1] : 0.f;
            float q2 = (f2 < end) ? csrN[f2] : 0.f;
            float q3 = (f3 < end) ? csrN[f3] : 0.f;
            uint_t u0 = Hq[(size_t)(isneg ? c0.y : c0.x) * 16 + sub];
            uint_t u1 = Hq[(size_t)(isneg ? c1.y : c1.x) * 16 + sub];
            uint_t u2 = Hq[(size_t)(isneg ? c2.y : c2.x) * 16 + sub];
            uint_t u3 = Hq[(size_t)(isneg ? c3.y : c3.x) * 16 + sub];
            floatx2 lo, hi;
            lo = __builtin_amdgcn_cvt_pk_f32_fp8(u0, false);
            hi = __builtin_amdgcn_cvt_pk_f32_fp8(u0, true);
            a0 = fmaf(lo.x, m0, a0); a1 = fmaf(lo.y, m0, a1);
            a2 = fmaf(hi.x, m0, a2); a3 = fmaf(hi.y, m0, a3);
            lo = __builtin_amdgcn_cvt_pk_f32_fp8(u1, false);
            hi = __builtin_amdgcn_cvt_pk_f32_fp8(u1, true);
            a0 = fmaf(lo.x, m1, a0); a1 = fmaf(lo.y, m1, a1);
            a2 = fmaf(hi.x, m1, a2); a3 = fmaf(hi.y, m1, a3);
            lo = __builtin_amdgcn_cvt_pk_f32_fp8(u2, false);
            hi = __builtin_amdgcn_cvt_pk_f32_fp8(u2, true);
            a0 = fmaf(lo.x, m2, a0); a1 = fmaf(lo.y, m2, a1);
            a2 = fmaf(hi.x, m2, a2); a3 = fmaf(hi.y, m2, a3);
            lo = __builtin_amdgcn_cvt_pk_f32_fp8(u3, false);
            hi = __builtin_amdgcn_cvt_pk_f32_fp8(u3, true);
            a0 = fmaf(lo.x, m3, a0); a1 = fmaf(lo.y, m3, a1);
            a2 = fmaf(hi.x, m3, a2); a3 = fmaf(hi.y, m3, a3);
            c0 = g0; c1 = g1; c2 = g2; c3 = g3;
            m0 = q0; m1 = q1; m2 = q2; m3 = q3;
        }
        a0 += __shfl_xor(a0, 32);
        a1 += __shfl_xor(a1, 32);
        a2 += __shfl_xor(a2, 32);
        a3 += __shfl_xor(a3, 32);
        int selfrow = isneg ? perm[n] : n;
        uint_t us = Hq[(size_t)selfrow * 16 + sub];
        floatx2 slo = __builtin_amdgcn_cvt_pk_f32_fp8(us, false);
        floatx2 shi = __builtin_amdgcn_cvt_pk_f32_fp8(us, true);
        float v0 = fmaf(slo.x, w2, a0) + b4.x;
        float v1 = fmaf(slo.y, w2, a1) + b4.y;
        float v2 = fmaf(shi.x, w2, a2) + b4.z;
        float v3 = fmaf(shi.y, w2, a3) + b4.w;
        v0 = v0 > 0.f ? v0 : v0 * a4.x;
        v1 = v1 > 0.f ? v1 : v1 * a4.y;
        v2 = v2 > 0.f ? v2 : v2 * a4.z;
        v3 = v3 > 0.f ? v3 : v3 * a4.w;
        if (lane < 32) {
            uint2 pk;
            pk.x = ((uint_t)f2bf(v1) << 16) | (uint_t)f2bf(v0);
            pk.y = ((uint_t)f2bf(v3) << 16) | (uint_t)f2bf(v2);
            uint2* outp = (uint2*)(isneg ? negb : posb);
            outp[(size_t)n * 16 + sub] = pk;
            if (!isneg) { s0 += v0; s1 += v1; s2 += v2; s3 += v3; }
        }
    }

    __shared__ float red[4][64];
    int w = tid >> 6;
    if (slot == 0) {
        red[w][sub * 4 + 0] = s0;
        red[w][sub * 4 + 1] = s1;
        red[w][sub * 4 + 2] = s2;
        red[w][sub * 4 + 3] = s3;
    }
    __syncthreads();
    if (tid < 64) {
        float s = red[0][tid] + red[1][tid] + red[2][tid] + red[3][tid];
        atomicAdd(&sumvec[tid], s);
    }
}

// ===== K5: loss (disc fused) + last-block final ============================
__global__ __launch_bounds__(256) void k_loss(const ushort_t* __restrict__ posb,
                                              const ushort_t* __restrict__ negb,
                                              float* __restrict__ smallb,
                                              const float* __restrict__ Wd,
                                              float* __restrict__ out, int N) {
    __shared__ float summ[64];
    __shared__ float svecS[64];
    __shared__ float redL[8];
    int tid = threadIdx.x;
    float* sumvec = smallb;
    float* lossAcc = smallb + 128;
    int* done = (int*)(smallb + 129);

    if (tid < 64) summ[tid] = 1.f / (1.f + expf(-sumvec[tid] / (float)N));
    __syncthreads();
    if (tid < 64) {
        float s = 0.f;
#pragma unroll
        for (int j = 0; j < 64; j++) s += Wd[tid * 64 + j] * summ[j];
        svecS[tid] = s;
    }
    __syncthreads();

    int lane = tid & 63;
    int half = lane >> 5;
    int sub = lane & 31;
    int w = tid >> 6;
    float s0 = svecS[2 * sub], s1 = svecS[2 * sub + 1];
    const uint_t* P32 = (const uint_t*)(half ? negb : posb);
    float l = 0.f;
    int wid = (blockIdx.x * 256 + tid) >> 6;
    int nw = gridDim.x * 4;
    for (int n = wid; n < N; n += nw) {
        uint_t u = P32[(size_t)n * 32 + sub];
        float p = lo_bf(u) * s0 + hi_bf(u) * s1;
        p += __shfl_xor(p, 1);
        p += __shfl_xor(p, 2);
        p += __shfl_xor(p, 4);
        p += __shfl_xor(p, 8);
        p += __shfl_xor(p, 16);
        if (sub == 0) l += half ? softplusf(p) : softplusf(-p);
    }
    if (sub == 0) redL[w * 2 + half] = l;
    __syncthreads();
    if (tid == 0) {
        float t = 0.f;
#pragma unroll
        for (int i = 0; i < 8; i++) t += redL[i];
        atomicAdd(&lossAcc[0], t);
        __threadfence();
        int old = atomicAdd(done, 1);
        if (old == (int)gridDim.x - 1) {
            float tot = atomicAdd(&lossAcc[0], 0.f);
            out[0] = tot / (float)N;
        }
    }
}

extern "C" void kernel_launch(void* const* d_in, const int* in_sizes, int n_in,
                              void* d_out, int out_size, void* d_ws, size_t ws_size,
                              hipStream_t stream) {
    const float* x      = (const float*)d_in[0];
    const float* W_gcn  = (const float*)d_in[1];
    const float* b_gcn  = (const float*)d_in[2];
    const float* prelu_a= (const float*)d_in[3];
    const float* W_disc = (const float*)d_in[4];
    const int*   eidx   = (const int*)d_in[5];
    const int*   perm   = (const int*)d_in[6];

    int N = in_sizes[0] / INDIM;      // 100000
    int E = in_sizes[5] / 2;          // 1600000
    const int* src = eidx;
    const int* dst = eidx + E;

    char* base = (char*)d_ws;
    size_t off = 0;
    auto alloc = [&](size_t bytes) { size_t o = off; off = (off + bytes + 255) & ~(size_t)255; return o; };
    uint_t*   Hq    = (uint_t*)  (base + alloc((size_t)N * HID));        // fp8: 6.4 MB
    ushort_t* posb  = (ushort_t*)(base + alloc((size_t)N * HID * 2));
    ushort_t* negb  = (ushort_t*)(base + alloc((size_t)N * HID * 2));
    int2*     csrS  = (int2*)   (base + alloc((size_t)E * 8));
    float*    csrN  = (float*)  (base + alloc((size_t)E * 4));
    int2*     ebuf  = (int2*)   (base + alloc((size_t)NBUCK * EBUF_PER * 8));
    int*      rowptr= (int*)    (base + alloc(((size_t)N + 1) * 4));
    float*    dinv  = (float*)  (base + alloc((size_t)N * 4));
    size_t zOff = alloc(NBUCK * 4 + 132 * 4);
    int*      bcur  = (int*)(base + zOff);
    float*    smallb= (float*)(base + zOff + NBUCK * 4);
    float* sumvec = smallb;

    int nbA = (E + CHUNK - 1) / CHUNK;    // 391
    int nbG = (N + 63) / 64;              // 1563
    int nbB = (N + 511) / 512;            // 196

    hipMemsetAsync(bcur, 0, NBUCK * 4 + 132 * 4, stream);
    k_fused<<<nbA + nbG, 256, 0, stream>>>(x, W_gcn, src, dst, Hq, bcur, ebuf, N, E, nbA);
    k_binB1<<<nbB, 256, 0, stream>>>(ebuf, bcur, rowptr, dinv, N, E);
    k_binB2<<<nbB, 256, 0, stream>>>(ebuf, bcur, rowptr, perm, dinv, csrS, csrN, N);
    k_gather<<<2048, 256, 0, stream>>>(Hq, rowptr, csrS, csrN, perm, dinv,
                                       b_gcn, prelu_a, posb, negb, sumvec, N);
    k_loss<<<512, 256, 0, stream>>>(posb, negb, smallb, W_disc, (float*)d_out, N);
}

// Round 15
// 261.401 us; speedup vs baseline: 1.2383x; 1.0025x over previous
//
#include <hip/hip_runtime.h>

#define HID 64
#define INDIM 128
#define NBUCK 256          // bucket = dst >> 9  (512 nodes/bucket)
#define EBUF_PER 10240     // fixed ebuf region per bucket (avg fill 8192, 22 sigma)
#define CHUNK 4096         // edges per binA block

typedef unsigned short ushort_t;
typedef unsigned int uint_t;
typedef float floatx2 __attribute__((ext_vector_type(2)));

__device__ __forceinline__ float softplusf(float x) {
    return fmaxf(x, 0.f) + log1pf(expf(-fabsf(x)));
}
__device__ __forceinline__ ushort_t f2bf(float f) {
    union { float f; uint_t i; } c; c.f = f;
    uint_t u = c.i;
    u += 0x7FFFu + ((u >> 16) & 1u);
    return (ushort_t)(u >> 16);
}
__device__ __forceinline__ float lo_bf(uint_t u) {
    union { uint_t i; float f; } c; c.i = u << 16; return c.f;
}
__device__ __forceinline__ float hi_bf(uint_t u) {
    union { uint_t i; float f; } c; c.i = u & 0xFFFF0000u; return c.f;
}

// ===== K1: fused [binA (blocks 0..nbA) | gemm (rest)] ======================
__global__ __launch_bounds__(256) void k_fused(const float* __restrict__ x,
                                               const float* __restrict__ W,
                                               const int* __restrict__ src,
                                               const int* __restrict__ dst,
                                               uint_t* __restrict__ Hq,
                                               int* __restrict__ bcur,
                                               int2* __restrict__ ebuf,
                                               int N, int E, int nbA) {
    __shared__ char lds[66560];
    int tid = threadIdx.x;

    if ((int)blockIdx.x < nbA) {
        // ---------------- binA ----------------
        int2* stage  = (int2*)lds;               // 32768
        int* lcnt    = (int*)(lds + 32768);
        int* binSt   = (int*)(lds + 33792);
        int* lofs    = (int*)(lds + 34816);
        int* gofs    = (int*)(lds + 35840);
        int* scn     = (int*)(lds + 36864);
        int base = blockIdx.x * CHUNK;

        lcnt[tid] = 0;
        __syncthreads();

        int sv[16], dv[16];
#pragma unroll
        for (int i = 0; i < 16; i++) {
            int e = base + i * 256 + tid;
            if (e < E) { sv[i] = src[e]; dv[i] = dst[e]; }
            else dv[i] = -1;
        }
#pragma unroll
        for (int i = 0; i < 16; i++)
            if (dv[i] >= 0) atomicAdd(&lcnt[dv[i] >> 9], 1);
        __syncthreads();

        scn[tid] = lcnt[tid];
        __syncthreads();
        for (int off = 1; off < NBUCK; off <<= 1) {
            int v = (tid >= off) ? scn[tid - off] : 0;
            __syncthreads();
            scn[tid] += v;
            __syncthreads();
        }
        binSt[tid] = scn[tid] - lcnt[tid];
        lofs[tid] = binSt[tid];
        __syncthreads();

#pragma unroll
        for (int i = 0; i < 16; i++) {
            if (dv[i] >= 0) {
                int b = dv[i] >> 9;
                int p = atomicAdd(&lofs[b], 1);
                stage[p] = make_int2(sv[i], dv[i]);
            }
        }
        __syncthreads();

        if (lcnt[tid] > 0)
            gofs[tid] = tid * EBUF_PER + atomicAdd(&bcur[tid], lcnt[tid]);
        __syncthreads();

        int total = (base + CHUNK <= E) ? CHUNK : (E > base ? E - base : 0);
        for (int idx = tid; idx < total; idx += 256) {
            int2 v = stage[idx];
            int b = v.y >> 9;
            ebuf[gofs[b] + (idx - binSt[b])] = v;
        }
    } else {
        // ---------------- gemm ----------------
        float* Xs = (float*)lds;                 // 33792
        float* Ws = (float*)(lds + 33792);       // 32768
        int row0 = ((int)blockIdx.x - nbA) * 64;

        const float4* W4 = (const float4*)W;
        float4* Ws4 = (float4*)Ws;
#pragma unroll
        for (int i = 0; i < 8; i++) Ws4[tid + 256 * i] = W4[tid + 256 * i];

#pragma unroll
        for (int i = 0; i < 8; i++) {
            int j = tid + 256 * i;
            int r = j >> 5, c4 = j & 31;
            int row = row0 + r;
            float4 v = make_float4(0.f, 0.f, 0.f, 0.f);
            if (row < N) v = *(const float4*)(x + row * INDIM + c4 * 4);
            *(float4*)(&Xs[r * 132 + c4 * 4]) = v;
        }
        __syncthreads();

        int tx = tid & 15;
        int ty = tid >> 4;
        float acc[4][4] = {};
        const float* xa = &Xs[(ty * 4) * 132];
#pragma unroll 4
        for (int k = 0; k < 128; k++) {
            float4 b = *(const float4*)(&Ws[k * 64 + tx * 4]);
#pragma unroll
            for (int i = 0; i < 4; i++) {
                float a = xa[i * 132 + k];
                acc[i][0] = fmaf(a, b.x, acc[i][0]);
                acc[i][1] = fmaf(a, b.y, acc[i][1]);
                acc[i][2] = fmaf(a, b.z, acc[i][2]);
                acc[i][3] = fmaf(a, b.w, acc[i][3]);
            }
        }
#pragma unroll
        for (int i = 0; i < 4; i++) {
            int row = row0 + ty * 4 + i;
            if (row < N) {
                uint_t u = 0;
                u = __builtin_amdgcn_cvt_pk_fp8_f32(acc[i][0], acc[i][1], u, false);
                u = __builtin_amdgcn_cvt_pk_fp8_f32(acc[i][2], acc[i][3], u, true);
                Hq[(size_t)row * 16 + tx] = u;
            }
        }
    }
}

// ===== K2: binB1 — per-bucket degrees -> rowptr, dinv ======================
__global__ __launch_bounds__(256) void k_binB1(const int2* __restrict__ ebuf,
                                               const int* __restrict__ bcur,
                                               int* __restrict__ rowptr,
                                               float* __restrict__ dinvg,
                                               int N, int E) {
    __shared__ int bb[NBUCK];
    __shared__ int sc[256];
    __shared__ int ldeg[512];
    int tid = threadIdx.x;
    int b = blockIdx.x;

    bb[tid] = bcur[tid];
    __syncthreads();
    for (int off = 1; off < NBUCK; off <<= 1) {
        int v = (tid >= off) ? bb[tid - off] : 0;
        __syncthreads();
        bb[tid] += v;
        __syncthreads();
    }
    int bucketBase = (b == 0) ? 0 : bb[b - 1];

    ldeg[tid] = 0;
    ldeg[tid + 256] = 0;
    __syncthreads();

    int start = b * EBUF_PER;
    int cb = bcur[b];
    for (int i = start + tid; i < start + cb; i += 256)
        atomicAdd(&ldeg[ebuf[i].y & 511], 1);
    __syncthreads();

    int d0 = ldeg[2 * tid], d1 = ldeg[2 * tid + 1];
    int s2 = d0 + d1;
    sc[tid] = s2;
    __syncthreads();
    for (int off = 1; off < 256; off <<= 1) {
        int v = (tid >= off) ? sc[tid - off] : 0;
        __syncthreads();
        sc[tid] += v;
        __syncthreads();
    }
    int ex = sc[tid] - s2;
    int n0 = (b << 9) + 2 * tid, n1 = n0 + 1;
    int r0 = bucketBase + ex, r1 = r0 + d0;
    if (n0 < N) { rowptr[n0] = r0; dinvg[n0] = rsqrtf((float)(d0 + 1)); }
    if (n1 < N) { rowptr[n1] = r1; dinvg[n1] = rsqrtf((float)(d1 + 1)); }
    if (b == 0 && tid == 0) rowptr[N] = E;
}

// ===== K3: binB2 — exact csr placement + precomputed norms =================
__global__ __launch_bounds__(256) void k_binB2(const int2* __restrict__ ebuf,
                                               const int* __restrict__ bcur,
                                               const int* __restrict__ rowptr,
                                               const int* __restrict__ perm,
                                               const float* __restrict__ dinvg,
                                               int2* __restrict__ csrS,
                                               float* __restrict__ csrN, int N) {
    __shared__ int lcur[512];
    __shared__ float ldinv[512];
    int tid = threadIdx.x;
    int b = blockIdx.x;
    int nodeBase = b << 9;
    for (int i = tid; i < 512; i += 256) {
        int n = nodeBase + i;
        lcur[i] = (n < N) ? rowptr[n] : 0;
        ldinv[i] = (n < N) ? dinvg[n] : 0.f;
    }
    __syncthreads();

    int start = b * EBUF_PER;
    int cb = bcur[b];
    for (int i = start + tid; i < start + cb; i += 256) {
        int2 v = ebuf[i];
        int s = v.x, dl = v.y & 511;
        int j = atomicAdd(&lcur[dl], 1);
        csrS[j] = make_int2(s, perm[s]);
        csrN[j] = dinvg[s] * ldinv[dl];
    }
}

// ===== K4: gather — fp8, slot layout, 3-stage pipeline (csr j+2, H j+1) ====
// lane = (slot, sub16); slot = (pair, isneg). Each H load = 4 rows x 64 B.
__global__ __launch_bounds__(256) void k_gather(const uint_t* __restrict__ Hq,
                                                const int* __restrict__ rowptr,
                                                const int2* __restrict__ csrS,
                                                const float* __restrict__ csrN,
                                                const int* __restrict__ perm,
                                                const float* __restrict__ dinv,
                                                const float* __restrict__ b,
                                                const float* __restrict__ a,
                                                ushort_t* __restrict__ posb,
                                                ushort_t* __restrict__ negb,
                                                float* __restrict__ sumvec, int N) {
    int tid = threadIdx.x;
    int lane = tid & 63;
    int slot = lane >> 4;
    int sub = lane & 15;
    int isneg = slot & 1;
    int pair = slot >> 1;
    int wid = (blockIdx.x * 256 + tid) >> 6;
    int nw = gridDim.x * 4;
    float4 b4 = ((const float4*)b)[sub];
    float4 a4 = ((const float4*)a)[sub];
    float s0 = 0.f, s1 = 0.f, s2 = 0.f, s3 = 0.f;

    for (int n = wid; n < N; n += nw) {
        float dv = dinv[n];
        float w2 = dv * dv;
        int beg = rowptr[n], end = rowptr[n + 1];
        float a0 = 0.f, a1 = 0.f, a2 = 0.f, a3 = 0.f;

        // ---- pipeline prologue ----
        // iter0 csr (cA/mA) and iter1 csr (cB/mB)
        int e0 = beg + pair, e1 = beg + 2 + pair, e2 = beg + 4 + pair, e3 = beg + 6 + pair;
        int2 cA0 = (e0 < end) ? csrS[e0] : make_int2(0, 0);
        int2 cA1 = (e1 < end) ? csrS[e1] : make_int2(0, 0);
        int2 cA2 = (e2 < end) ? csrS[e2] : make_int2(0, 0);
        int2 cA3 = (e3 < end) ? csrS[e3] : make_int2(0, 0);
        float mA0 = (e0 < end) ? csrN[e0] : 0.f;
        float mA1 = (e1 < end) ? csrN[e1] : 0.f;
        float mA2 = (e2 < end) ? csrN[e2] : 0.f;
        float mA3 = (e3 < end) ? csrN[e3] : 0.f;
        int f0 = e0 + 8, f1 = e1 + 8, f2 = e2 + 8, f3 = e3 + 8;
        int2 cB0 = (f0 < end) ? csrS[f0] : make_int2(0, 0);
        int2 cB1 = (f1 < end) ? csrS[f1] : make_int2(0, 0);
        int2 cB2 = (f2 < end) ? csrS[f2] : make_int2(0, 0);
        int2 cB3 = (f3 < end) ? csrS[f3] : make_int2(0, 0);
        float mB0 = (f0 < end) ? csrN[f0] : 0.f;
        float mB1 = (f1 < end) ? csrN[f1] : 0.f;
        float mB2 = (f2 < end) ? csrN[f2] : 0.f;
        float mB3 = (f3 < end) ? csrN[f3] : 0.f;
        // iter0 H values (uc) — in flight while loop body runs
        uint_t uc0 = Hq[(size_t)(isneg ? cA0.y : cA0.x) * 16 + sub];
        uint_t uc1 = Hq[(size_t)(isneg ? cA1.y : cA1.x) * 16 + sub];
        uint_t uc2 = Hq[(size_t)(isneg ? cA2.y : cA2.x) * 16 + sub];
        uint_t uc3 = Hq[(size_t)(isneg ? cA3.y : cA3.x) * 16 + sub];

        for (int j = beg; j < end; j += 8) {
            // stage 1: csr for iter j+16 (two ahead)
            int g0 = j + 16 + pair, g1 = j + 18 + pair, g2 = j + 20 + pair, g3 = j + 22 + pair;
            int2 cC0 = (g0 < end) ? csrS[g0] : make_int2(0, 0);
            int2 cC1 = (g1 < end) ? csrS[g1] : make_int2(0, 0);
            int2 cC2 = (g2 < end) ? csrS[g2] : make_int2(0, 0);
            int2 cC3 = (g3 < end) ? csrS[g3] : make_int2(0, 0);
            float mC0 = (g0 < end) ? csrN[g0] : 0.f;
            float mC1 = (g1 < end) ? csrN[g1] : 0.f;
            float mC2 = (g2 < end) ? csrN[g2] : 0.f;
            float mC3 = (g3 < end) ? csrN[g3] : 0.f;
            // stage 2: H loads for iter j+8 (indices prefetched last iter)
            uint_t un0 = Hq[(size_t)(isneg ? cB0.y : cB0.x) * 16 + sub];
            uint_t un1 = Hq[(size_t)(isneg ? cB1.y : cB1.x) * 16 + sub];
            uint_t un2 = Hq[(size_t)(isneg ? cB2.y : cB2.x) * 16 + sub];
            uint_t un3 = Hq[(size_t)(isneg ? cB3.y : cB3.x) * 16 + sub];
            // stage 3: consume iter j's H values (issued a full iter ago)
            floatx2 lo, hi;
            lo = __builtin_amdgcn_cvt_pk_f32_fp8(uc0, false);
            hi = __builtin_amdgcn_cvt_pk_f32_fp8(uc0, true);
            a0 = fmaf(lo.x, mA0, a0); a1 = fmaf(lo.y, mA0, a1);
            a2 = fmaf(hi.x, mA0, a2); a3 = fmaf(hi.y, mA0, a3);
            lo = __builtin_amdgcn_cvt_pk_f32_fp8(uc1, false);
            hi = __builtin_amdgcn_cvt_pk_f32_fp8(uc1, true);
            a0 = fmaf(lo.x, mA1, a0); a1 = fmaf(lo.y, mA1, a1);
            a2 = fmaf(hi.x, mA1, a2); a3 = fmaf(hi.y, mA1, a3);
            lo = __builtin_amdgcn_cvt_pk_f32_fp8(uc2, false);
            hi = __builtin_amdgcn_cvt_pk_f32_fp8(uc2, true);
            a0 = fmaf(lo.x, mA2, a0); a1 = fmaf(lo.y, mA2, a1);
            a2 = fmaf(hi.x, mA2, a2); a3 = fmaf(hi.y, mA2, a3);
            lo = __builtin_amdgcn_cvt_pk_f32_fp8(uc3, false);
            hi = __builtin_amdgcn_cvt_pk_f32_fp8(uc3, true);
            a0 = fmaf(lo.x, mA3, a0); a1 = fmaf(lo.y, mA3, a1);
            a2 = fmaf(hi.x, mA3, a2); a3 = fmaf(hi.y, mA3, a3);
            // rotate pipeline
            mA0 = mB0; mA1 = mB1; mA2 = mB2; mA3 = mB3;
            cB0 = cC0; cB1 = cC1; cB2 = cC2; cB3 = cC3;
            mB0 = mC0; mB1 = mC1; mB2 = mC2; mB3 = mC3;
            uc0 = un0; uc1 = un1; uc2 = un2; uc3 = un3;
        }
        a0 += __shfl_xor(a0, 32);
        a1 += __shfl_xor(a1, 32);
        a2 += __shfl_xor(a2, 32);
        a3 += __shfl_xor(a3, 32);
        int selfrow = isneg ? perm[n] : n;
        uint_t us = Hq[(size_t)selfrow * 16 + sub];
        floatx2 slo = __builtin_amdgcn_cvt_pk_f32_fp8(us, false);
        floatx2 shi = __builtin_amdgcn_cvt_pk_f32_fp8(us, true);
        float v0 = fmaf(slo.x, w2, a0) + b4.x;
        float v1 = fmaf(slo.y, w2, a1) + b4.y;
        float v2 = fmaf(shi.x, w2, a2) + b4.z;
        float v3 = fmaf(shi.y, w2, a3) + b4.w;
        v0 = v0 > 0.f ? v0 : v0 * a4.x;
        v1 = v1 > 0.f ? v1 : v1 * a4.y;
        v2 = v2 > 0.f ? v2 : v2 * a4.z;
        v3 = v3 > 0.f ? v3 : v3 * a4.w;
        if (lane < 32) {
            uint2 pk;
            pk.x = ((uint_t)f2bf(v1) << 16) | (uint_t)f2bf(v0);
            pk.y = ((uint_t)f2bf(v3) << 16) | (uint_t)f2bf(v2);
            uint2* outp = (uint2*)(isneg ? negb : posb);
            outp[(size_t)n * 16 + sub] = pk;
            if (!isneg) { s0 += v0; s1 += v1; s2 += v2; s3 += v3; }
        }
    }

    __shared__ float red[4][64];
    int w = tid >> 6;
    if (slot == 0) {
        red[w][sub * 4 + 0] = s0;
        red[w][sub * 4 + 1] = s1;
        red[w][sub * 4 + 2] = s2;
        red[w][sub * 4 + 3] = s3;
    }
    __syncthreads();
    if (tid < 64) {
        float s = red[0][tid] + red[1][tid] + red[2][tid] + red[3][tid];
        atomicAdd(&sumvec[tid], s);
    }
}

// ===== K5: loss (disc fused) + last-block final ============================
__global__ __launch_bounds__(256) void k_loss(const ushort_t* __restrict__ posb,
                                              const ushort_t* __restrict__ negb,
                                              float* __restrict__ smallb,
                                              const float* __restrict__ Wd,
                                              float* __restrict__ out, int N) {
    __shared__ float summ[64];
    __shared__ float svecS[64];
    __shared__ float redL[8];
    int tid = threadIdx.x;
    float* sumvec = smallb;
    float* lossAcc = smallb + 128;
    int* done = (int*)(smallb + 129);

    if (tid < 64) summ[tid] = 1.f / (1.f + expf(-sumvec[tid] / (float)N));
    __syncthreads();
    if (tid < 64) {
        float s = 0.f;
#pragma unroll
        for (int j = 0; j < 64; j++) s += Wd[tid * 64 + j] * summ[j];
        svecS[tid] = s;
    }
    __syncthreads();

    int lane = tid & 63;
    int half = lane >> 5;
    int sub = lane & 31;
    int w = tid >> 6;
    float s0 = svecS[2 * sub], s1 = svecS[2 * sub + 1];
    const uint_t* P32 = (const uint_t*)(half ? negb : posb);
    float l = 0.f;
    int wid = (blockIdx.x * 256 + tid) >> 6;
    int nw = gridDim.x * 4;
    for (int n = wid; n < N; n += nw) {
        uint_t u = P32[(size_t)n * 32 + sub];
        float p = lo_bf(u) * s0 + hi_bf(u) * s1;
        p += __shfl_xor(p, 1);
        p += __shfl_xor(p, 2);
        p += __shfl_xor(p, 4);
        p += __shfl_xor(p, 8);
        p += __shfl_xor(p, 16);
        if (sub == 0) l += half ? softplusf(p) : softplusf(-p);
    }
    if (sub == 0) redL[w * 2 + half] = l;
    __syncthreads();
    if (tid == 0) {
        float t = 0.f;
#pragma unroll
        for (int i = 0; i < 8; i++) t += redL[i];
        atomicAdd(&lossAcc[0], t);
        __threadfence();
        int old = atomicAdd(done, 1);
        if (old == (int)gridDim.x - 1) {
            float tot = atomicAdd(&lossAcc[0], 0.f);
            out[0] = tot / (float)N;
        }
    }
}

extern "C" void kernel_launch(void* const* d_in, const int* in_sizes, int n_in,
                              void* d_out, int out_size, void* d_ws, size_t ws_size,
                              hipStream_t stream) {
    const float* x      = (const float*)d_in[0];
    const float* W_gcn  = (const float*)d_in[1];
    const float* b_gcn  = (const float*)d_in[2];
    const float* prelu_a= (const float*)d_in[3];
    const float* W_disc = (const float*)d_in[4];
    const int*   eidx   = (const int*)d_in[5];
    const int*   perm   = (const int*)d_in[6];

    int N = in_sizes[0] / INDIM;      // 100000
    int E = in_sizes[5] / 2;          // 1600000
    const int* src = eidx;
    const int* dst = eidx + E;

    char* base = (char*)d_ws;
    size_t off = 0;
    auto alloc = [&](size_t bytes) { size_t o = off; off = (off + bytes + 255) & ~(size_t)255; return o; };
    uint_t*   Hq    = (uint_t*)  (base + alloc((size_t)N * HID));        // fp8: 6.4 MB
    ushort_t* posb  = (ushort_t*)(base + alloc((size_t)N * HID * 2));
    ushort_t* negb  = (ushort_t*)(base + alloc((size_t)N * HID * 2));
    int2*     csrS  = (int2*)   (base + alloc((size_t)E * 8));
    float*    csrN  = (float*)  (base + alloc((size_t)E * 4));
    int2*     ebuf  = (int2*)   (base + alloc((size_t)NBUCK * EBUF_PER * 8));
    int*      rowptr= (int*)    (base + alloc(((size_t)N + 1) * 4));
    float*    dinv  = (float*)  (base + alloc((size_t)N * 4));
    size_t zOff = alloc(NBUCK * 4 + 132 * 4);
    int*      bcur  = (int*)(base + zOff);
    float*    smallb= (float*)(base + zOff + NBUCK * 4);
    float* sumvec = smallb;

    int nbA = (E + CHUNK - 1) / CHUNK;    // 391
    int nbG = (N + 63) / 64;              // 1563
    int nbB = (N + 511) / 512;            // 196

    hipMemsetAsync(bcur, 0, NBUCK * 4 + 132 * 4, stream);
    k_fused<<<nbA + nbG, 256, 0, stream>>>(x, W_gcn, src, dst, Hq, bcur, ebuf, N, E, nbA);
    k_binB1<<<nbB, 256, 0, stream>>>(ebuf, bcur, rowptr, dinv, N, E);
    k_binB2<<<nbB, 256, 0, stream>>>(ebuf, bcur, rowptr, perm, dinv, csrS, csrN, N);
    k_gather<<<2048, 256, 0, stream>>>(Hq, rowptr, csrS, csrN, perm, dinv,
                                       b_gcn, prelu_a, posb, negb, sumvec, N);
    k_loss<<<512, 256, 0, stream>>>(posb, negb, smallb, W_disc, (float*)d_out, N);
}